// Round 6
// baseline (684.109 us; speedup 1.0000x reference)
//
#include <hip/hip_runtime.h>

// ChebNet fp32, round 6: two-level counting sort for CSR (cache-friendly
// writes), 2x-unrolled prop. GEMMs unchanged from R5.

// ---------- CSR build ----------

__global__ void k_hist(const int* __restrict__ dst, int* __restrict__ cnt, int E) {
    int e = blockIdx.x * blockDim.x + threadIdx.x;
    if (e < E) atomicAdd(&cnt[dst[e]], 1);
}

__global__ void k_blocksum(const int* __restrict__ cnt, int* __restrict__ bsum, int N) {
    __shared__ int red[256];
    int i = blockIdx.x * 256 + threadIdx.x;
    red[threadIdx.x] = (i < N) ? cnt[i] : 0;
    __syncthreads();
    for (int s = 128; s > 0; s >>= 1) {
        if (threadIdx.x < s) red[threadIdx.x] += red[threadIdx.x + s];
        __syncthreads();
    }
    if (threadIdx.x == 0) bsum[blockIdx.x] = red[0];
}

__global__ void k_scanbsum(int* bsum, int nb) {
    __shared__ int sh[1024];
    int tid = threadIdx.x;
    int v = (tid < nb) ? bsum[tid] : 0;
    sh[tid] = v;
    __syncthreads();
    for (int off = 1; off < 1024; off <<= 1) {
        int t = 0;
        if (tid >= off) t = sh[tid - off];
        __syncthreads();
        sh[tid] += t;
        __syncthreads();
    }
    if (tid < nb) bsum[tid] = sh[tid] - v;
}

__global__ void k_scanfinal(const int* __restrict__ cnt, const int* __restrict__ bsum,
                            int* __restrict__ row_ptr, float* __restrict__ dinv,
                            int N, int E) {
    __shared__ int sh[256];
    int i = blockIdx.x * 256 + threadIdx.x;
    int v = (i < N) ? cnt[i] : 0;
    sh[threadIdx.x] = v;
    __syncthreads();
    for (int off = 1; off < 256; off <<= 1) {
        int t = 0;
        if (threadIdx.x >= off) t = sh[threadIdx.x - off];
        __syncthreads();
        sh[threadIdx.x] += t;
        __syncthreads();
    }
    int excl = sh[threadIdx.x] - v + bsum[blockIdx.x];
    if (i < N) {
        row_ptr[i] = excl;
        dinv[i] = rsqrtf(fmaxf((float)v, 1.0f));
    }
    if (blockIdx.x == 0 && threadIdx.x == 0) row_ptr[N] = E;
}

// bucket cursors init: bucket b covers dst [b*128, (b+1)*128)
__global__ void k_binit(const int* __restrict__ row_ptr, int* __restrict__ bcur, int NB) {
    int b = blockIdx.x * blockDim.x + threadIdx.x;
    if (b < NB) bcur[b] = row_ptr[b << 7];
}

// pass B: scatter (src,dst) into bucket regions (sequential-per-bucket writes)
__global__ void k_bucket(const int* __restrict__ src, const int* __restrict__ dst,
                         int* __restrict__ bcur, int2* __restrict__ eb, int E) {
    int e = blockIdx.x * blockDim.x + threadIdx.x;
    if (e < E) {
        int d = dst[e];
        int p = atomicAdd(&bcur[d >> 7], 1);
        eb[p] = make_int2(src[e], d);
    }
}

// pass C: one block per bucket; LDS per-dst cursors; write final cw
// (positions land in the bucket's contiguous range -> line-local writes)
__global__ __launch_bounds__(256) void k_local(
    const int2* __restrict__ eb, const int* __restrict__ row_ptr,
    const float* __restrict__ dinv, int2* __restrict__ cw, int N) {
    __shared__ int lcur[128];
    int b = blockIdx.x;
    int d0 = b << 7;
    int dN = d0 + 128; if (dN > N) dN = N;
    int nd = dN - d0;
    if (threadIdx.x < nd) lcur[threadIdx.x] = row_ptr[d0 + threadIdx.x];
    __syncthreads();
    int beg = row_ptr[d0], end = row_ptr[dN];
    for (int i = beg + threadIdx.x; i < end; i += 256) {
        int2 ed = eb[i];
        int p = atomicAdd(&lcur[ed.y - d0], 1);
        cw[p] = make_int2(ed.x, __float_as_int(dinv[ed.x]));
    }
}

// ---------- propagation (wide gather, 2x unrolled) ----------
template <int MODE>
__global__ __launch_bounds__(256) void k_prop(
    const float* __restrict__ X, const int* __restrict__ rp,
    const int2* __restrict__ cw, const float* __restrict__ dinv,
    const float* __restrict__ X0, float* __restrict__ OUT, int N) {
    int wid = (blockIdx.x * blockDim.x + threadIdx.x) >> 6;
    int lane = threadIdx.x & 63;
    if (wid >= N) return;
    int g = lane >> 4;
    int fl = (lane & 15) * 4;
    int beg = rp[wid], end = rp[wid + 1];
    float4 a0 = make_float4(0.f, 0.f, 0.f, 0.f);
    float4 a1 = make_float4(0.f, 0.f, 0.f, 0.f);
    int e = beg + g;
    for (; e + 4 < end; e += 8) {
        int2 c0 = cw[e];
        int2 c1 = cw[e + 4];
        float w0 = __int_as_float(c0.y);
        float w1 = __int_as_float(c1.y);
        float4 v0 = *(const float4*)&X[(size_t)c0.x * 64 + fl];
        float4 v1 = *(const float4*)&X[(size_t)c1.x * 64 + fl];
        a0.x = fmaf(v0.x, w0, a0.x);
        a0.y = fmaf(v0.y, w0, a0.y);
        a0.z = fmaf(v0.z, w0, a0.z);
        a0.w = fmaf(v0.w, w0, a0.w);
        a1.x = fmaf(v1.x, w1, a1.x);
        a1.y = fmaf(v1.y, w1, a1.y);
        a1.z = fmaf(v1.z, w1, a1.z);
        a1.w = fmaf(v1.w, w1, a1.w);
    }
    if (e < end) {
        int2 c0 = cw[e];
        float w0 = __int_as_float(c0.y);
        float4 v0 = *(const float4*)&X[(size_t)c0.x * 64 + fl];
        a0.x = fmaf(v0.x, w0, a0.x);
        a0.y = fmaf(v0.y, w0, a0.y);
        a0.z = fmaf(v0.z, w0, a0.z);
        a0.w = fmaf(v0.w, w0, a0.w);
    }
    float4 acc;
    acc.x = a0.x + a1.x;
    acc.y = a0.y + a1.y;
    acc.z = a0.z + a1.z;
    acc.w = a0.w + a1.w;
    acc.x += __shfl_xor(acc.x, 16);
    acc.y += __shfl_xor(acc.y, 16);
    acc.z += __shfl_xor(acc.z, 16);
    acc.w += __shfl_xor(acc.w, 16);
    acc.x += __shfl_xor(acc.x, 32);
    acc.y += __shfl_xor(acc.y, 32);
    acc.z += __shfl_xor(acc.z, 32);
    acc.w += __shfl_xor(acc.w, 32);
    if (g == 0) {
        float di = dinv[wid];
        float4 o;
        if (MODE == 1) {
            o.x = -di * acc.x; o.y = -di * acc.y; o.z = -di * acc.z; o.w = -di * acc.w;
        } else {
            float4 x0 = *(const float4*)&X0[(size_t)wid * 64 + fl];
            float m = -2.0f * di;
            o.x = fmaf(m, acc.x, -x0.x);
            o.y = fmaf(m, acc.y, -x0.y);
            o.z = fmaf(m, acc.z, -x0.z);
            o.w = fmaf(m, acc.w, -x0.w);
        }
        *(float4*)&OUT[(size_t)wid * 64 + fl] = o;
    }
}

// ---------- cheb linear: Y[N,64] = relu([X0|X1|X2] @ W[192,64] + b) ----------
__global__ __launch_bounds__(256) void k_cheb_gemm(
    const float* __restrict__ X0, const float* __restrict__ X1,
    const float* __restrict__ X2, const float* __restrict__ W,
    const float* __restrict__ b, float* __restrict__ Y, int N) {
    __shared__ float Ws[64][64];
    __shared__ float Xs[64][68];
    __shared__ float bs[64];
    int t = threadIdx.x;
    if (t < 64) bs[t] = b[t];

    int c4 = (t & 15) * 4;
    int r4 = (t >> 4) * 4;
    int node0 = blockIdx.x * 64;
    float acc[4][4] = {{0}};

    const float* Xp[3] = {X0, X1, X2};
#pragma unroll 1
    for (int chunk = 0; chunk < 3; chunk++) {
        __syncthreads();
        {
            const float* Wc = W + chunk * 64 * 64;
            for (int i = t; i < 64 * 16; i += 256) {
                int r = i >> 4, c = (i & 15) * 4;
                *(float4*)&Ws[r][c] = *(const float4*)&Wc[r * 64 + c];
            }
        }
        {
            const float* X = Xp[chunk];
            int f4 = (t & 15) * 4;
            int nl0 = t >> 4;
            for (int p = 0; p < 4; p++) {
                int nl = nl0 + p * 16;
                int node = node0 + nl;
                float4 v = make_float4(0.f, 0.f, 0.f, 0.f);
                if (node < N) v = *(const float4*)&X[(size_t)node * 64 + f4];
                *(float4*)&Xs[nl][f4] = v;
            }
        }
        __syncthreads();
#pragma unroll 4
        for (int k4 = 0; k4 < 64; k4 += 4) {
            float4 xv[4], wv[4];
#pragma unroll
            for (int i = 0; i < 4; i++) xv[i] = *(const float4*)&Xs[r4 + i][k4];
#pragma unroll
            for (int q = 0; q < 4; q++) wv[q] = *(const float4*)&Ws[k4 + q][c4];
#pragma unroll
            for (int i = 0; i < 4; i++) {
                acc[i][0] = fmaf(xv[i].x, wv[0].x, acc[i][0]);
                acc[i][1] = fmaf(xv[i].x, wv[0].y, acc[i][1]);
                acc[i][2] = fmaf(xv[i].x, wv[0].z, acc[i][2]);
                acc[i][3] = fmaf(xv[i].x, wv[0].w, acc[i][3]);
                acc[i][0] = fmaf(xv[i].y, wv[1].x, acc[i][0]);
                acc[i][1] = fmaf(xv[i].y, wv[1].y, acc[i][1]);
                acc[i][2] = fmaf(xv[i].y, wv[1].z, acc[i][2]);
                acc[i][3] = fmaf(xv[i].y, wv[1].w, acc[i][3]);
                acc[i][0] = fmaf(xv[i].z, wv[2].x, acc[i][0]);
                acc[i][1] = fmaf(xv[i].z, wv[2].y, acc[i][1]);
                acc[i][2] = fmaf(xv[i].z, wv[2].z, acc[i][2]);
                acc[i][3] = fmaf(xv[i].z, wv[2].w, acc[i][3]);
                acc[i][0] = fmaf(xv[i].w, wv[3].x, acc[i][0]);
                acc[i][1] = fmaf(xv[i].w, wv[3].y, acc[i][1]);
                acc[i][2] = fmaf(xv[i].w, wv[3].z, acc[i][2]);
                acc[i][3] = fmaf(xv[i].w, wv[3].w, acc[i][3]);
            }
        }
    }
#pragma unroll
    for (int i = 0; i < 4; i++) {
        int row = node0 + r4 + i;
        if (row < N) {
            float4 o;
            o.x = fmaxf(acc[i][0] + bs[c4 + 0], 0.0f);
            o.y = fmaxf(acc[i][1] + bs[c4 + 1], 0.0f);
            o.z = fmaxf(acc[i][2] + bs[c4 + 2], 0.0f);
            o.w = fmaxf(acc[i][3] + bs[c4 + 3], 0.0f);
            *(float4*)&Y[(size_t)row * 64 + c4] = o;
        }
    }
}

// ---------- MLP head ----------
__global__ __launch_bounds__(256) void k_mlp_gemm(
    const float* __restrict__ H, const float* __restrict__ Wm1,
    const float* __restrict__ bm1, const float* __restrict__ Wm2,
    const float* __restrict__ bm2, float* __restrict__ out, int N) {
    __shared__ float W1s[64][64];
    __shared__ float W2s[64][32];
    __shared__ float Hs[64][68];
    __shared__ float b1s[64];
    __shared__ float b2s[32];
    int t = threadIdx.x;
    for (int i = t; i < 64 * 16; i += 256) {
        int r = i >> 4, c = (i & 15) * 4;
        *(float4*)&W1s[r][c] = *(const float4*)&Wm1[r * 64 + c];
    }
    for (int i = t; i < 64 * 8; i += 256) {
        int r = i >> 3, c = (i & 7) * 4;
        *(float4*)&W2s[r][c] = *(const float4*)&Wm2[r * 32 + c];
    }
    if (t < 64) b1s[t] = bm1[t];
    else if (t < 96) b2s[t - 64] = bm2[t - 64];

    int node0 = blockIdx.x * 64;
    {
        int f4 = (t & 15) * 4;
        int nl0 = t >> 4;
        for (int p = 0; p < 4; p++) {
            int nl = nl0 + p * 16;
            int node = node0 + nl;
            float4 v = make_float4(0.f, 0.f, 0.f, 0.f);
            if (node < N) v = *(const float4*)&H[(size_t)node * 64 + f4];
            *(float4*)&Hs[nl][f4] = v;
        }
    }
    __syncthreads();

    float acc[4][4] = {{0}};
    int c4 = (t & 15) * 4;
    int r4 = (t >> 4) * 4;
#pragma unroll 4
    for (int k4 = 0; k4 < 64; k4 += 4) {
        float4 xv[4], wv[4];
#pragma unroll
        for (int i = 0; i < 4; i++) xv[i] = *(const float4*)&Hs[r4 + i][k4];
#pragma unroll
        for (int q = 0; q < 4; q++) wv[q] = *(const float4*)&W1s[k4 + q][c4];
#pragma unroll
        for (int i = 0; i < 4; i++) {
            acc[i][0] = fmaf(xv[i].x, wv[0].x, acc[i][0]);
            acc[i][1] = fmaf(xv[i].x, wv[0].y, acc[i][1]);
            acc[i][2] = fmaf(xv[i].x, wv[0].z, acc[i][2]);
            acc[i][3] = fmaf(xv[i].x, wv[0].w, acc[i][3]);
            acc[i][0] = fmaf(xv[i].y, wv[1].x, acc[i][0]);
            acc[i][1] = fmaf(xv[i].y, wv[1].y, acc[i][1]);
            acc[i][2] = fmaf(xv[i].y, wv[1].z, acc[i][2]);
            acc[i][3] = fmaf(xv[i].y, wv[1].w, acc[i][3]);
            acc[i][0] = fmaf(xv[i].z, wv[2].x, acc[i][0]);
            acc[i][1] = fmaf(xv[i].z, wv[2].y, acc[i][1]);
            acc[i][2] = fmaf(xv[i].z, wv[2].z, acc[i][2]);
            acc[i][3] = fmaf(xv[i].z, wv[2].w, acc[i][3]);
            acc[i][0] = fmaf(xv[i].w, wv[3].x, acc[i][0]);
            acc[i][1] = fmaf(xv[i].w, wv[3].y, acc[i][1]);
            acc[i][2] = fmaf(xv[i].w, wv[3].z, acc[i][2]);
            acc[i][3] = fmaf(xv[i].w, wv[3].w, acc[i][3]);
        }
    }
    __syncthreads();
#pragma unroll
    for (int i = 0; i < 4; i++) {
        float4 o;
        o.x = fmaxf(acc[i][0] + b1s[c4 + 0], 0.0f);
        o.y = fmaxf(acc[i][1] + b1s[c4 + 1], 0.0f);
        o.z = fmaxf(acc[i][2] + b1s[c4 + 2], 0.0f);
        o.w = fmaxf(acc[i][3] + b1s[c4 + 3], 0.0f);
        *(float4*)&Hs[r4 + i][c4] = o;
    }
    __syncthreads();

    {
        int cc4 = (t & 7) * 4;
        int r2 = (t >> 3) * 2;
        float a2[2][4] = {{0}};
#pragma unroll 4
        for (int k4 = 0; k4 < 64; k4 += 4) {
            float4 xv[2], wv[4];
#pragma unroll
            for (int i = 0; i < 2; i++) xv[i] = *(const float4*)&Hs[r2 + i][k4];
#pragma unroll
            for (int q = 0; q < 4; q++) wv[q] = *(const float4*)&W2s[k4 + q][cc4];
#pragma unroll
            for (int i = 0; i < 2; i++) {
                a2[i][0] = fmaf(xv[i].x, wv[0].x, a2[i][0]);
                a2[i][1] = fmaf(xv[i].x, wv[0].y, a2[i][1]);
                a2[i][2] = fmaf(xv[i].x, wv[0].z, a2[i][2]);
                a2[i][3] = fmaf(xv[i].x, wv[0].w, a2[i][3]);
                a2[i][0] = fmaf(xv[i].y, wv[1].x, a2[i][0]);
                a2[i][1] = fmaf(xv[i].y, wv[1].y, a2[i][1]);
                a2[i][2] = fmaf(xv[i].y, wv[1].z, a2[i][2]);
                a2[i][3] = fmaf(xv[i].y, wv[1].w, a2[i][3]);
                a2[i][0] = fmaf(xv[i].z, wv[2].x, a2[i][0]);
                a2[i][1] = fmaf(xv[i].z, wv[2].y, a2[i][1]);
                a2[i][2] = fmaf(xv[i].z, wv[2].z, a2[i][2]);
                a2[i][3] = fmaf(xv[i].z, wv[2].w, a2[i][3]);
                a2[i][0] = fmaf(xv[i].w, wv[3].x, a2[i][0]);
                a2[i][1] = fmaf(xv[i].w, wv[3].y, a2[i][1]);
                a2[i][2] = fmaf(xv[i].w, wv[3].z, a2[i][2]);
                a2[i][3] = fmaf(xv[i].w, wv[3].w, a2[i][3]);
            }
        }
#pragma unroll
        for (int i = 0; i < 2; i++) {
            int row = node0 + r2 + i;
            if (row < N) {
                float4 o;
                o.x = a2[i][0] + b2s[cc4 + 0];
                o.y = a2[i][1] + b2s[cc4 + 1];
                o.z = a2[i][2] + b2s[cc4 + 2];
                o.w = a2[i][3] + b2s[cc4 + 3];
                *(float4*)&out[(size_t)row * 32 + cc4] = o;
            }
        }
    }
}

extern "C" void kernel_launch(void* const* d_in, const int* in_sizes, int n_in,
                              void* d_out, int out_size, void* d_ws, size_t ws_size,
                              hipStream_t stream) {
    const float* features = (const float*)d_in[0];
    const int* src = (const int*)d_in[1];
    const int* dst = (const int*)d_in[2];
    const float* W1 = (const float*)d_in[4];
    const float* b1 = (const float*)d_in[5];
    const float* W2 = (const float*)d_in[6];
    const float* b2 = (const float*)d_in[7];
    const float* Wm1 = (const float*)d_in[8];
    const float* bm1 = (const float*)d_in[9];
    const float* Wm2 = (const float*)d_in[10];
    const float* bm2 = (const float*)d_in[11];
    float* out = (float*)d_out;

    int N = in_sizes[0] / 64;
    int E = in_sizes[1];
    int NB = (N + 127) >> 7;  // dst buckets of 128

    float* ws = (float*)d_ws;
    float* dinv = ws;                        // [N]
    float* B1 = ws + N;                      // [N,64] X1
    float* B2 = B1 + (size_t)N * 64;         // [N,64] X2
    float* B3 = B2 + (size_t)N * 64;         // [N,64] H2
    float* B4 = B3 + (size_t)N * 64;         // [N,64] H1
    int* row_ptr = (int*)(B4 + (size_t)N * 64);   // [N+1]
    int* cnt = row_ptr + (N + 1);                 // [N]
    int* bsum = cnt + N;                          // [<=1024]
    int* bcur = bsum + 1024;                      // [<=1024]
    int2* cw = (int2*)(((uintptr_t)(bcur + 1024) + 7) & ~(uintptr_t)7);  // [E]
    int2* eb = (int2*)B1;  // temp bucket buffer aliases B1 (free until prop1)

    int eblk = (E + 255) / 256;
    int nblk = (N + 255) / 256;
    int pblk = (N * 64 + 255) / 256;
    int gblk = (N + 63) / 64;

    // CSR build: hist -> scan -> bucket scatter -> per-bucket local sort
    hipMemsetAsync(cnt, 0, (size_t)N * sizeof(int), stream);
    k_hist<<<eblk, 256, 0, stream>>>(dst, cnt, E);
    k_blocksum<<<nblk, 256, 0, stream>>>(cnt, bsum, N);
    k_scanbsum<<<1, 1024, 0, stream>>>(bsum, nblk);
    k_scanfinal<<<nblk, 256, 0, stream>>>(cnt, bsum, row_ptr, dinv, N, E);
    k_binit<<<(NB + 255) / 256, 256, 0, stream>>>(row_ptr, bcur, NB);
    k_bucket<<<eblk, 256, 0, stream>>>(src, dst, bcur, eb, E);
    k_local<<<NB, 256, 0, stream>>>(eb, row_ptr, dinv, cw, N);

    // layer 1
    k_prop<1><<<pblk, 256, 0, stream>>>(features, row_ptr, cw, dinv, nullptr, B1, N);
    k_prop<2><<<pblk, 256, 0, stream>>>(B1, row_ptr, cw, dinv, features, B2, N);
    k_cheb_gemm<<<gblk, 256, 0, stream>>>(features, B1, B2, W1, b1, B4, N);

    // layer 2
    k_prop<1><<<pblk, 256, 0, stream>>>(B4, row_ptr, cw, dinv, nullptr, B1, N);
    k_prop<2><<<pblk, 256, 0, stream>>>(B1, row_ptr, cw, dinv, B4, B2, N);
    k_cheb_gemm<<<gblk, 256, 0, stream>>>(B4, B1, B2, W2, b2, B3, N);

    // MLP head
    k_mlp_gemm<<<gblk, 256, 0, stream>>>(B3, Wm1, bm1, Wm2, bm2, out, N);
}

// Round 7
// 488.811 us; speedup vs baseline: 1.3995x; 1.3995x over previous
//
#include <hip/hip_runtime.h>

// ChebNet, round 7: R5 CSR (single-pass place) + bf16 gather rows in prop
// (fp32 accumulate, fp32 everywhere else). Write-amplification lesson from
// R6: random scatter costs ~E*64B in writebacks regardless of payload size;
// bucket pre-pass serializes on cursor atomics -> reverted.

typedef unsigned short ushort_t;

__device__ inline ushort_t f2bf(float f) {  // RNE float->bf16
    unsigned u = __float_as_uint(f);
    return (ushort_t)((u + 0x7FFFu + ((u >> 16) & 1u)) >> 16);
}
__device__ inline float bf2f(ushort_t h) {
    return __uint_as_float(((unsigned)h) << 16);
}

// ---------- CSR build (R5 version) ----------

__global__ void k_hist(const int* __restrict__ dst, int* __restrict__ cnt, int E) {
    int e = blockIdx.x * blockDim.x + threadIdx.x;
    if (e < E) atomicAdd(&cnt[dst[e]], 1);
}

__global__ void k_blocksum(const int* __restrict__ cnt, int* __restrict__ bsum, int N) {
    __shared__ int red[256];
    int i = blockIdx.x * 256 + threadIdx.x;
    red[threadIdx.x] = (i < N) ? cnt[i] : 0;
    __syncthreads();
    for (int s = 128; s > 0; s >>= 1) {
        if (threadIdx.x < s) red[threadIdx.x] += red[threadIdx.x + s];
        __syncthreads();
    }
    if (threadIdx.x == 0) bsum[blockIdx.x] = red[0];
}

__global__ void k_scanbsum(int* bsum, int nb) {
    __shared__ int sh[1024];
    int tid = threadIdx.x;
    int v = (tid < nb) ? bsum[tid] : 0;
    sh[tid] = v;
    __syncthreads();
    for (int off = 1; off < 1024; off <<= 1) {
        int t = 0;
        if (tid >= off) t = sh[tid - off];
        __syncthreads();
        sh[tid] += t;
        __syncthreads();
    }
    if (tid < nb) bsum[tid] = sh[tid] - v;
}

__global__ void k_scanfinal(const int* __restrict__ cnt, const int* __restrict__ bsum,
                            int* __restrict__ row_ptr, int* __restrict__ cursor,
                            float* __restrict__ dinv, int N, int E) {
    __shared__ int sh[256];
    int i = blockIdx.x * 256 + threadIdx.x;
    int v = (i < N) ? cnt[i] : 0;
    sh[threadIdx.x] = v;
    __syncthreads();
    for (int off = 1; off < 256; off <<= 1) {
        int t = 0;
        if (threadIdx.x >= off) t = sh[threadIdx.x - off];
        __syncthreads();
        sh[threadIdx.x] += t;
        __syncthreads();
    }
    int excl = sh[threadIdx.x] - v + bsum[blockIdx.x];
    if (i < N) {
        row_ptr[i] = excl;
        cursor[i] = excl;
        dinv[i] = rsqrtf(fmaxf((float)v, 1.0f));
    }
    if (blockIdx.x == 0 && threadIdx.x == 0) row_ptr[N] = E;
}

__global__ void k_place(const int* __restrict__ src, const int* __restrict__ dst,
                        const float* __restrict__ dinv,
                        int* __restrict__ cursor, int2* __restrict__ cw, int E) {
    int e = blockIdx.x * blockDim.x + threadIdx.x;
    if (e < E) {
        int s = src[e];
        int p = atomicAdd(&cursor[dst[e]], 1);
        cw[p] = make_int2(s, __float_as_int(dinv[s]));
    }
}

// ---------- fp32 -> bf16 copy ----------
__global__ void k_tobf16(const float4* __restrict__ X, ushort4* __restrict__ Y, int n4) {
    int i = blockIdx.x * blockDim.x + threadIdx.x;
    if (i < n4) {
        float4 v = X[i];
        ushort4 o;
        o.x = f2bf(v.x); o.y = f2bf(v.y); o.z = f2bf(v.z); o.w = f2bf(v.w);
        Y[i] = o;
    }
}

// ---------- propagation: gather bf16 rows, fp32 accumulate ----------
// wave = dst node; 4 groups of 16 lanes, group g takes edges beg+g+4k;
// lane loads ushort4 (4 feats). MODE 1: OUT=-dinv*sum; MODE 2: OUT=-2*dinv*sum-X0.
// WB: also write bf16 shadow of OUT (for the next prop's gather).
template <int MODE, bool WB>
__global__ __launch_bounds__(256) void k_prop(
    const ushort_t* __restrict__ Xb, const int* __restrict__ rp,
    const int2* __restrict__ cw, const float* __restrict__ dinv,
    const float* __restrict__ X0, float* __restrict__ OUT,
    ushort_t* __restrict__ OUTB, int N) {
    int wid = (blockIdx.x * blockDim.x + threadIdx.x) >> 6;
    int lane = threadIdx.x & 63;
    if (wid >= N) return;
    int g = lane >> 4;
    int fl = (lane & 15) * 4;
    int beg = rp[wid], end = rp[wid + 1];
    float4 a0 = make_float4(0.f, 0.f, 0.f, 0.f);
    float4 a1 = make_float4(0.f, 0.f, 0.f, 0.f);
    int e = beg + g;
    for (; e + 4 < end; e += 8) {
        int2 c0 = cw[e];
        int2 c1 = cw[e + 4];
        float w0 = __int_as_float(c0.y);
        float w1 = __int_as_float(c1.y);
        ushort4 u0 = *(const ushort4*)&Xb[(size_t)c0.x * 64 + fl];
        ushort4 u1 = *(const ushort4*)&Xb[(size_t)c1.x * 64 + fl];
        a0.x = fmaf(bf2f(u0.x), w0, a0.x);
        a0.y = fmaf(bf2f(u0.y), w0, a0.y);
        a0.z = fmaf(bf2f(u0.z), w0, a0.z);
        a0.w = fmaf(bf2f(u0.w), w0, a0.w);
        a1.x = fmaf(bf2f(u1.x), w1, a1.x);
        a1.y = fmaf(bf2f(u1.y), w1, a1.y);
        a1.z = fmaf(bf2f(u1.z), w1, a1.z);
        a1.w = fmaf(bf2f(u1.w), w1, a1.w);
    }
    if (e < end) {
        int2 c0 = cw[e];
        float w0 = __int_as_float(c0.y);
        ushort4 u0 = *(const ushort4*)&Xb[(size_t)c0.x * 64 + fl];
        a0.x = fmaf(bf2f(u0.x), w0, a0.x);
        a0.y = fmaf(bf2f(u0.y), w0, a0.y);
        a0.z = fmaf(bf2f(u0.z), w0, a0.z);
        a0.w = fmaf(bf2f(u0.w), w0, a0.w);
    }
    float4 acc;
    acc.x = a0.x + a1.x;
    acc.y = a0.y + a1.y;
    acc.z = a0.z + a1.z;
    acc.w = a0.w + a1.w;
    acc.x += __shfl_xor(acc.x, 16);
    acc.y += __shfl_xor(acc.y, 16);
    acc.z += __shfl_xor(acc.z, 16);
    acc.w += __shfl_xor(acc.w, 16);
    acc.x += __shfl_xor(acc.x, 32);
    acc.y += __shfl_xor(acc.y, 32);
    acc.z += __shfl_xor(acc.z, 32);
    acc.w += __shfl_xor(acc.w, 32);
    if (g == 0) {
        float di = dinv[wid];
        float4 o;
        if (MODE == 1) {
            o.x = -di * acc.x; o.y = -di * acc.y; o.z = -di * acc.z; o.w = -di * acc.w;
        } else {
            float4 x0 = *(const float4*)&X0[(size_t)wid * 64 + fl];
            float m = -2.0f * di;
            o.x = fmaf(m, acc.x, -x0.x);
            o.y = fmaf(m, acc.y, -x0.y);
            o.z = fmaf(m, acc.z, -x0.z);
            o.w = fmaf(m, acc.w, -x0.w);
        }
        *(float4*)&OUT[(size_t)wid * 64 + fl] = o;
        if (WB) {
            ushort4 ob;
            ob.x = f2bf(o.x); ob.y = f2bf(o.y); ob.z = f2bf(o.z); ob.w = f2bf(o.w);
            *(ushort4*)&OUTB[(size_t)wid * 64 + fl] = ob;
        }
    }
}

// ---------- cheb linear: Y = relu([X0|X1|X2] @ W[192,64] + b) ----------
// optional bf16 shadow output Yb (for next layer's gathers)
__global__ __launch_bounds__(256) void k_cheb_gemm(
    const float* __restrict__ X0, const float* __restrict__ X1,
    const float* __restrict__ X2, const float* __restrict__ W,
    const float* __restrict__ b, float* __restrict__ Y,
    ushort_t* __restrict__ Yb, int N) {
    __shared__ float Ws[64][64];
    __shared__ float Xs[64][68];
    __shared__ float bs[64];
    int t = threadIdx.x;
    if (t < 64) bs[t] = b[t];

    int c4 = (t & 15) * 4;
    int r4 = (t >> 4) * 4;
    int node0 = blockIdx.x * 64;
    float acc[4][4] = {{0}};

    const float* Xp[3] = {X0, X1, X2};
#pragma unroll 1
    for (int chunk = 0; chunk < 3; chunk++) {
        __syncthreads();
        {
            const float* Wc = W + chunk * 64 * 64;
            for (int i = t; i < 64 * 16; i += 256) {
                int r = i >> 4, c = (i & 15) * 4;
                *(float4*)&Ws[r][c] = *(const float4*)&Wc[r * 64 + c];
            }
        }
        {
            const float* X = Xp[chunk];
            int f4 = (t & 15) * 4;
            int nl0 = t >> 4;
            for (int p = 0; p < 4; p++) {
                int nl = nl0 + p * 16;
                int node = node0 + nl;
                float4 v = make_float4(0.f, 0.f, 0.f, 0.f);
                if (node < N) v = *(const float4*)&X[(size_t)node * 64 + f4];
                *(float4*)&Xs[nl][f4] = v;
            }
        }
        __syncthreads();
#pragma unroll 4
        for (int k4 = 0; k4 < 64; k4 += 4) {
            float4 xv[4], wv[4];
#pragma unroll
            for (int i = 0; i < 4; i++) xv[i] = *(const float4*)&Xs[r4 + i][k4];
#pragma unroll
            for (int q = 0; q < 4; q++) wv[q] = *(const float4*)&Ws[k4 + q][c4];
#pragma unroll
            for (int i = 0; i < 4; i++) {
                acc[i][0] = fmaf(xv[i].x, wv[0].x, acc[i][0]);
                acc[i][1] = fmaf(xv[i].x, wv[0].y, acc[i][1]);
                acc[i][2] = fmaf(xv[i].x, wv[0].z, acc[i][2]);
                acc[i][3] = fmaf(xv[i].x, wv[0].w, acc[i][3]);
                acc[i][0] = fmaf(xv[i].y, wv[1].x, acc[i][0]);
                acc[i][1] = fmaf(xv[i].y, wv[1].y, acc[i][1]);
                acc[i][2] = fmaf(xv[i].y, wv[1].z, acc[i][2]);
                acc[i][3] = fmaf(xv[i].y, wv[1].w, acc[i][3]);
                acc[i][0] = fmaf(xv[i].z, wv[2].x, acc[i][0]);
                acc[i][1] = fmaf(xv[i].z, wv[2].y, acc[i][1]);
                acc[i][2] = fmaf(xv[i].z, wv[2].z, acc[i][2]);
                acc[i][3] = fmaf(xv[i].z, wv[2].w, acc[i][3]);
                acc[i][0] = fmaf(xv[i].w, wv[3].x, acc[i][0]);
                acc[i][1] = fmaf(xv[i].w, wv[3].y, acc[i][1]);
                acc[i][2] = fmaf(xv[i].w, wv[3].z, acc[i][2]);
                acc[i][3] = fmaf(xv[i].w, wv[3].w, acc[i][3]);
            }
        }
    }
#pragma unroll
    for (int i = 0; i < 4; i++) {
        int row = node0 + r4 + i;
        if (row < N) {
            float4 o;
            o.x = fmaxf(acc[i][0] + bs[c4 + 0], 0.0f);
            o.y = fmaxf(acc[i][1] + bs[c4 + 1], 0.0f);
            o.z = fmaxf(acc[i][2] + bs[c4 + 2], 0.0f);
            o.w = fmaxf(acc[i][3] + bs[c4 + 3], 0.0f);
            *(float4*)&Y[(size_t)row * 64 + c4] = o;
            if (Yb) {
                ushort4 ob;
                ob.x = f2bf(o.x); ob.y = f2bf(o.y); ob.z = f2bf(o.z); ob.w = f2bf(o.w);
                *(ushort4*)&Yb[(size_t)row * 64 + c4] = ob;
            }
        }
    }
}

// ---------- MLP head ----------
__global__ __launch_bounds__(256) void k_mlp_gemm(
    const float* __restrict__ H, const float* __restrict__ Wm1,
    const float* __restrict__ bm1, const float* __restrict__ Wm2,
    const float* __restrict__ bm2, float* __restrict__ out, int N) {
    __shared__ float W1s[64][64];
    __shared__ float W2s[64][32];
    __shared__ float Hs[64][68];
    __shared__ float b1s[64];
    __shared__ float b2s[32];
    int t = threadIdx.x;
    for (int i = t; i < 64 * 16; i += 256) {
        int r = i >> 4, c = (i & 15) * 4;
        *(float4*)&W1s[r][c] = *(const float4*)&Wm1[r * 64 + c];
    }
    for (int i = t; i < 64 * 8; i += 256) {
        int r = i >> 3, c = (i & 7) * 4;
        *(float4*)&W2s[r][c] = *(const float4*)&Wm2[r * 32 + c];
    }
    if (t < 64) b1s[t] = bm1[t];
    else if (t < 96) b2s[t - 64] = bm2[t - 64];

    int node0 = blockIdx.x * 64;
    {
        int f4 = (t & 15) * 4;
        int nl0 = t >> 4;
        for (int p = 0; p < 4; p++) {
            int nl = nl0 + p * 16;
            int node = node0 + nl;
            float4 v = make_float4(0.f, 0.f, 0.f, 0.f);
            if (node < N) v = *(const float4*)&H[(size_t)node * 64 + f4];
            *(float4*)&Hs[nl][f4] = v;
        }
    }
    __syncthreads();

    float acc[4][4] = {{0}};
    int c4 = (t & 15) * 4;
    int r4 = (t >> 4) * 4;
#pragma unroll 4
    for (int k4 = 0; k4 < 64; k4 += 4) {
        float4 xv[4], wv[4];
#pragma unroll
        for (int i = 0; i < 4; i++) xv[i] = *(const float4*)&Hs[r4 + i][k4];
#pragma unroll
        for (int q = 0; q < 4; q++) wv[q] = *(const float4*)&W1s[k4 + q][c4];
#pragma unroll
        for (int i = 0; i < 4; i++) {
            acc[i][0] = fmaf(xv[i].x, wv[0].x, acc[i][0]);
            acc[i][1] = fmaf(xv[i].x, wv[0].y, acc[i][1]);
            acc[i][2] = fmaf(xv[i].x, wv[0].z, acc[i][2]);
            acc[i][3] = fmaf(xv[i].x, wv[0].w, acc[i][3]);
            acc[i][0] = fmaf(xv[i].y, wv[1].x, acc[i][0]);
            acc[i][1] = fmaf(xv[i].y, wv[1].y, acc[i][1]);
            acc[i][2] = fmaf(xv[i].y, wv[1].z, acc[i][2]);
            acc[i][3] = fmaf(xv[i].y, wv[1].w, acc[i][3]);
            acc[i][0] = fmaf(xv[i].z, wv[2].x, acc[i][0]);
            acc[i][1] = fmaf(xv[i].z, wv[2].y, acc[i][1]);
            acc[i][2] = fmaf(xv[i].z, wv[2].z, acc[i][2]);
            acc[i][3] = fmaf(xv[i].z, wv[2].w, acc[i][3]);
            acc[i][0] = fmaf(xv[i].w, wv[3].x, acc[i][0]);
            acc[i][1] = fmaf(xv[i].w, wv[3].y, acc[i][1]);
            acc[i][2] = fmaf(xv[i].w, wv[3].z, acc[i][2]);
            acc[i][3] = fmaf(xv[i].w, wv[3].w, acc[i][3]);
        }
    }
    __syncthreads();
#pragma unroll
    for (int i = 0; i < 4; i++) {
        float4 o;
        o.x = fmaxf(acc[i][0] + b1s[c4 + 0], 0.0f);
        o.y = fmaxf(acc[i][1] + b1s[c4 + 1], 0.0f);
        o.z = fmaxf(acc[i][2] + b1s[c4 + 2], 0.0f);
        o.w = fmaxf(acc[i][3] + b1s[c4 + 3], 0.0f);
        *(float4*)&Hs[r4 + i][c4] = o;
    }
    __syncthreads();

    {
        int cc4 = (t & 7) * 4;
        int r2 = (t >> 3) * 2;
        float a2[2][4] = {{0}};
#pragma unroll 4
        for (int k4 = 0; k4 < 64; k4 += 4) {
            float4 xv[2], wv[4];
#pragma unroll
            for (int i = 0; i < 2; i++) xv[i] = *(const float4*)&Hs[r2 + i][k4];
#pragma unroll
            for (int q = 0; q < 4; q++) wv[q] = *(const float4*)&W2s[k4 + q][cc4];
#pragma unroll
            for (int i = 0; i < 2; i++) {
                a2[i][0] = fmaf(xv[i].x, wv[0].x, a2[i][0]);
                a2[i][1] = fmaf(xv[i].x, wv[0].y, a2[i][1]);
                a2[i][2] = fmaf(xv[i].x, wv[0].z, a2[i][2]);
                a2[i][3] = fmaf(xv[i].x, wv[0].w, a2[i][3]);
                a2[i][0] = fmaf(xv[i].y, wv[1].x, a2[i][0]);
                a2[i][1] = fmaf(xv[i].y, wv[1].y, a2[i][1]);
                a2[i][2] = fmaf(xv[i].y, wv[1].z, a2[i][2]);
                a2[i][3] = fmaf(xv[i].y, wv[1].w, a2[i][3]);
                a2[i][0] = fmaf(xv[i].z, wv[2].x, a2[i][0]);
                a2[i][1] = fmaf(xv[i].z, wv[2].y, a2[i][1]);
                a2[i][2] = fmaf(xv[i].z, wv[2].z, a2[i][2]);
                a2[i][3] = fmaf(xv[i].z, wv[2].w, a2[i][3]);
                a2[i][0] = fmaf(xv[i].w, wv[3].x, a2[i][0]);
                a2[i][1] = fmaf(xv[i].w, wv[3].y, a2[i][1]);
                a2[i][2] = fmaf(xv[i].w, wv[3].z, a2[i][2]);
                a2[i][3] = fmaf(xv[i].w, wv[3].w, a2[i][3]);
            }
        }
#pragma unroll
        for (int i = 0; i < 2; i++) {
            int row = node0 + r2 + i;
            if (row < N) {
                float4 o;
                o.x = a2[i][0] + b2s[cc4 + 0];
                o.y = a2[i][1] + b2s[cc4 + 1];
                o.z = a2[i][2] + b2s[cc4 + 2];
                o.w = a2[i][3] + b2s[cc4 + 3];
                *(float4*)&out[(size_t)row * 32 + cc4] = o;
            }
        }
    }
}

extern "C" void kernel_launch(void* const* d_in, const int* in_sizes, int n_in,
                              void* d_out, int out_size, void* d_ws, size_t ws_size,
                              hipStream_t stream) {
    const float* features = (const float*)d_in[0];
    const int* src = (const int*)d_in[1];
    const int* dst = (const int*)d_in[2];
    const float* W1 = (const float*)d_in[4];
    const float* b1 = (const float*)d_in[5];
    const float* W2 = (const float*)d_in[6];
    const float* b2 = (const float*)d_in[7];
    const float* Wm1 = (const float*)d_in[8];
    const float* bm1 = (const float*)d_in[9];
    const float* Wm2 = (const float*)d_in[10];
    const float* bm2 = (const float*)d_in[11];
    float* out = (float*)d_out;

    int N = in_sizes[0] / 64;
    int E = in_sizes[1];

    float* ws = (float*)d_ws;
    float* dinv = ws;                        // [N]
    float* B1 = ws + N;                      // [N,64] X1
    float* B2 = B1 + (size_t)N * 64;         // [N,64] X2
    float* B3 = B2 + (size_t)N * 64;         // [N,64] H2
    float* B4 = B3 + (size_t)N * 64;         // [N,64] H1
    int* row_ptr = (int*)(B4 + (size_t)N * 64);   // [N+1]
    int* cursor = row_ptr + (N + 1);              // [N]
    int* bsum = cursor + N;                       // [1024]
    int2* cw = (int2*)(((uintptr_t)(bsum + 1024) + 7) & ~(uintptr_t)7);  // [E]
    // bf16 shadows
    ushort_t* Fb  = (ushort_t*)(cw + E);          // [N*64]
    ushort_t* B1b = Fb + (size_t)N * 64;          // [N*64]
    ushort_t* B4b = B1b + (size_t)N * 64;         // [N*64]

    int eblk = (E + 255) / 256;
    int nblk = (N + 255) / 256;
    int pblk = (N * 64 + 255) / 256;
    int gblk = (N + 63) / 64;
    int n4 = N * 16;
    int cblk = (n4 + 255) / 256;

    // CSR build
    hipMemsetAsync(cursor, 0, (size_t)N * sizeof(int), stream);
    k_hist<<<eblk, 256, 0, stream>>>(dst, cursor, E);
    k_blocksum<<<nblk, 256, 0, stream>>>(cursor, bsum, N);
    k_scanbsum<<<1, 1024, 0, stream>>>(bsum, nblk);
    k_scanfinal<<<nblk, 256, 0, stream>>>(cursor, bsum, row_ptr, cursor, dinv, N, E);
    k_place<<<eblk, 256, 0, stream>>>(src, dst, dinv, cursor, cw, E);

    // bf16 shadow of features
    k_tobf16<<<cblk, 256, 0, stream>>>((const float4*)features, (ushort4*)Fb, n4);

    // layer 1
    k_prop<1, true><<<pblk, 256, 0, stream>>>(Fb, row_ptr, cw, dinv, nullptr, B1, B1b, N);
    k_prop<2, false><<<pblk, 256, 0, stream>>>(B1b, row_ptr, cw, dinv, features, B2, nullptr, N);
    k_cheb_gemm<<<gblk, 256, 0, stream>>>(features, B1, B2, W1, b1, B4, B4b, N);

    // layer 2
    k_prop<1, true><<<pblk, 256, 0, stream>>>(B4b, row_ptr, cw, dinv, nullptr, B1, B1b, N);
    k_prop<2, false><<<pblk, 256, 0, stream>>>(B1b, row_ptr, cw, dinv, B4, B2, nullptr, N);
    k_cheb_gemm<<<gblk, 256, 0, stream>>>(B4, B1, B2, W2, b2, B3, nullptr, N);

    // MLP head
    k_mlp_gemm<<<gblk, 256, 0, stream>>>(B3, Wm1, bm1, Wm2, bm2, out, N);
}

// Round 8
// 488.325 us; speedup vs baseline: 1.4009x; 1.0010x over previous
//
#include <hip/hip_runtime.h>

// ChebNet round 8: all-bf16 intermediates (fp32 accumulate + fp32 weights +
// fp32 final out). Props write only bf16; GEMMs read bf16 tiles, write bf16.
// CSR build unchanged from R5/R7.

typedef unsigned short ushort_t;

__device__ inline ushort_t f2bf(float f) {  // RNE float->bf16
    unsigned u = __float_as_uint(f);
    return (ushort_t)((u + 0x7FFFu + ((u >> 16) & 1u)) >> 16);
}
__device__ inline float bf2f(ushort_t h) {
    return __uint_as_float(((unsigned)h) << 16);
}

// ---------- CSR build ----------

__global__ void k_hist(const int* __restrict__ dst, int* __restrict__ cnt, int E) {
    int e = blockIdx.x * blockDim.x + threadIdx.x;
    if (e < E) atomicAdd(&cnt[dst[e]], 1);
}

__global__ void k_blocksum(const int* __restrict__ cnt, int* __restrict__ bsum, int N) {
    __shared__ int red[256];
    int i = blockIdx.x * 256 + threadIdx.x;
    red[threadIdx.x] = (i < N) ? cnt[i] : 0;
    __syncthreads();
    for (int s = 128; s > 0; s >>= 1) {
        if (threadIdx.x < s) red[threadIdx.x] += red[threadIdx.x + s];
        __syncthreads();
    }
    if (threadIdx.x == 0) bsum[blockIdx.x] = red[0];
}

__global__ void k_scanbsum(int* bsum, int nb) {
    __shared__ int sh[1024];
    int tid = threadIdx.x;
    int v = (tid < nb) ? bsum[tid] : 0;
    sh[tid] = v;
    __syncthreads();
    for (int off = 1; off < 1024; off <<= 1) {
        int t = 0;
        if (tid >= off) t = sh[tid - off];
        __syncthreads();
        sh[tid] += t;
        __syncthreads();
    }
    if (tid < nb) bsum[tid] = sh[tid] - v;
}

__global__ void k_scanfinal(const int* __restrict__ cnt, const int* __restrict__ bsum,
                            int* __restrict__ row_ptr, int* __restrict__ cursor,
                            float* __restrict__ dinv, int N, int E) {
    __shared__ int sh[256];
    int i = blockIdx.x * 256 + threadIdx.x;
    int v = (i < N) ? cnt[i] : 0;
    sh[threadIdx.x] = v;
    __syncthreads();
    for (int off = 1; off < 256; off <<= 1) {
        int t = 0;
        if (threadIdx.x >= off) t = sh[threadIdx.x - off];
        __syncthreads();
        sh[threadIdx.x] += t;
        __syncthreads();
    }
    int excl = sh[threadIdx.x] - v + bsum[blockIdx.x];
    if (i < N) {
        row_ptr[i] = excl;
        cursor[i] = excl;
        dinv[i] = rsqrtf(fmaxf((float)v, 1.0f));
    }
    if (blockIdx.x == 0 && threadIdx.x == 0) row_ptr[N] = E;
}

__global__ void k_place(const int* __restrict__ src, const int* __restrict__ dst,
                        const float* __restrict__ dinv,
                        int* __restrict__ cursor, int2* __restrict__ cw, int E) {
    int e = blockIdx.x * blockDim.x + threadIdx.x;
    if (e < E) {
        int s = src[e];
        int p = atomicAdd(&cursor[dst[e]], 1);
        cw[p] = make_int2(s, __float_as_int(dinv[s]));
    }
}

// ---------- fp32 -> bf16 copy ----------
__global__ void k_tobf16(const float4* __restrict__ X, ushort4* __restrict__ Y, int n4) {
    int i = blockIdx.x * blockDim.x + threadIdx.x;
    if (i < n4) {
        float4 v = X[i];
        ushort4 o;
        o.x = f2bf(v.x); o.y = f2bf(v.y); o.z = f2bf(v.z); o.w = f2bf(v.w);
        Y[i] = o;
    }
}

// ---------- propagation: all-bf16 I/O, fp32 accumulate ----------
// wave = dst node; 4 groups of 16 lanes; lane loads ushort4 (4 feats).
// MODE 1: OUT = bf16(-dinv*sum); MODE 2: OUT = bf16(-2*dinv*sum - X0b)
template <int MODE>
__global__ __launch_bounds__(256) void k_prop(
    const ushort_t* __restrict__ Xb, const int* __restrict__ rp,
    const int2* __restrict__ cw, const float* __restrict__ dinv,
    const ushort_t* __restrict__ X0b, ushort_t* __restrict__ OUTB, int N) {
    int wid = (blockIdx.x * blockDim.x + threadIdx.x) >> 6;
    int lane = threadIdx.x & 63;
    if (wid >= N) return;
    int g = lane >> 4;
    int fl = (lane & 15) * 4;
    int beg = rp[wid], end = rp[wid + 1];
    float4 a0 = make_float4(0.f, 0.f, 0.f, 0.f);
    float4 a1 = make_float4(0.f, 0.f, 0.f, 0.f);
    int e = beg + g;
    for (; e + 4 < end; e += 8) {
        int2 c0 = cw[e];
        int2 c1 = cw[e + 4];
        float w0 = __int_as_float(c0.y);
        float w1 = __int_as_float(c1.y);
        ushort4 u0 = *(const ushort4*)&Xb[(size_t)c0.x * 64 + fl];
        ushort4 u1 = *(const ushort4*)&Xb[(size_t)c1.x * 64 + fl];
        a0.x = fmaf(bf2f(u0.x), w0, a0.x);
        a0.y = fmaf(bf2f(u0.y), w0, a0.y);
        a0.z = fmaf(bf2f(u0.z), w0, a0.z);
        a0.w = fmaf(bf2f(u0.w), w0, a0.w);
        a1.x = fmaf(bf2f(u1.x), w1, a1.x);
        a1.y = fmaf(bf2f(u1.y), w1, a1.y);
        a1.z = fmaf(bf2f(u1.z), w1, a1.z);
        a1.w = fmaf(bf2f(u1.w), w1, a1.w);
    }
    if (e < end) {
        int2 c0 = cw[e];
        float w0 = __int_as_float(c0.y);
        ushort4 u0 = *(const ushort4*)&Xb[(size_t)c0.x * 64 + fl];
        a0.x = fmaf(bf2f(u0.x), w0, a0.x);
        a0.y = fmaf(bf2f(u0.y), w0, a0.y);
        a0.z = fmaf(bf2f(u0.z), w0, a0.z);
        a0.w = fmaf(bf2f(u0.w), w0, a0.w);
    }
    float4 acc;
    acc.x = a0.x + a1.x;
    acc.y = a0.y + a1.y;
    acc.z = a0.z + a1.z;
    acc.w = a0.w + a1.w;
    acc.x += __shfl_xor(acc.x, 16);
    acc.y += __shfl_xor(acc.y, 16);
    acc.z += __shfl_xor(acc.z, 16);
    acc.w += __shfl_xor(acc.w, 16);
    acc.x += __shfl_xor(acc.x, 32);
    acc.y += __shfl_xor(acc.y, 32);
    acc.z += __shfl_xor(acc.z, 32);
    acc.w += __shfl_xor(acc.w, 32);
    if (g == 0) {
        float di = dinv[wid];
        float4 o;
        if (MODE == 1) {
            o.x = -di * acc.x; o.y = -di * acc.y; o.z = -di * acc.z; o.w = -di * acc.w;
        } else {
            ushort4 x0u = *(const ushort4*)&X0b[(size_t)wid * 64 + fl];
            float m = -2.0f * di;
            o.x = fmaf(m, acc.x, -bf2f(x0u.x));
            o.y = fmaf(m, acc.y, -bf2f(x0u.y));
            o.z = fmaf(m, acc.z, -bf2f(x0u.z));
            o.w = fmaf(m, acc.w, -bf2f(x0u.w));
        }
        ushort4 ob;
        ob.x = f2bf(o.x); ob.y = f2bf(o.y); ob.z = f2bf(o.z); ob.w = f2bf(o.w);
        *(ushort4*)&OUTB[(size_t)wid * 64 + fl] = ob;
    }
}

// ---------- cheb linear: Yb = bf16(relu([X0|X1|X2] @ W[192,64] + b)) ----------
// bf16 inputs -> fp32 LDS tiles -> fp32 FMA -> bf16 output.
__global__ __launch_bounds__(256) void k_cheb_gemm(
    const ushort_t* __restrict__ X0, const ushort_t* __restrict__ X1,
    const ushort_t* __restrict__ X2, const float* __restrict__ W,
    const float* __restrict__ b, ushort_t* __restrict__ Yb, int N) {
    __shared__ float Ws[64][64];
    __shared__ float Xs[64][68];
    __shared__ float bs[64];
    int t = threadIdx.x;
    if (t < 64) bs[t] = b[t];

    int c4 = (t & 15) * 4;
    int r4 = (t >> 4) * 4;
    int node0 = blockIdx.x * 64;
    float acc[4][4] = {{0}};

    const ushort_t* Xp[3] = {X0, X1, X2};
#pragma unroll 1
    for (int chunk = 0; chunk < 3; chunk++) {
        __syncthreads();
        {
            const float* Wc = W + chunk * 64 * 64;
            for (int i = t; i < 64 * 16; i += 256) {
                int r = i >> 4, c = (i & 15) * 4;
                *(float4*)&Ws[r][c] = *(const float4*)&Wc[r * 64 + c];
            }
        }
        {
            const ushort_t* X = Xp[chunk];
            int f4 = (t & 15) * 4;
            int nl0 = t >> 4;
            for (int p = 0; p < 4; p++) {
                int nl = nl0 + p * 16;
                int node = node0 + nl;
                float4 v = make_float4(0.f, 0.f, 0.f, 0.f);
                if (node < N) {
                    ushort4 u = *(const ushort4*)&X[(size_t)node * 64 + f4];
                    v = make_float4(bf2f(u.x), bf2f(u.y), bf2f(u.z), bf2f(u.w));
                }
                *(float4*)&Xs[nl][f4] = v;
            }
        }
        __syncthreads();
#pragma unroll 4
        for (int k4 = 0; k4 < 64; k4 += 4) {
            float4 xv[4], wv[4];
#pragma unroll
            for (int i = 0; i < 4; i++) xv[i] = *(const float4*)&Xs[r4 + i][k4];
#pragma unroll
            for (int q = 0; q < 4; q++) wv[q] = *(const float4*)&Ws[k4 + q][c4];
#pragma unroll
            for (int i = 0; i < 4; i++) {
                acc[i][0] = fmaf(xv[i].x, wv[0].x, acc[i][0]);
                acc[i][1] = fmaf(xv[i].x, wv[0].y, acc[i][1]);
                acc[i][2] = fmaf(xv[i].x, wv[0].z, acc[i][2]);
                acc[i][3] = fmaf(xv[i].x, wv[0].w, acc[i][3]);
                acc[i][0] = fmaf(xv[i].y, wv[1].x, acc[i][0]);
                acc[i][1] = fmaf(xv[i].y, wv[1].y, acc[i][1]);
                acc[i][2] = fmaf(xv[i].y, wv[1].z, acc[i][2]);
                acc[i][3] = fmaf(xv[i].y, wv[1].w, acc[i][3]);
                acc[i][0] = fmaf(xv[i].z, wv[2].x, acc[i][0]);
                acc[i][1] = fmaf(xv[i].z, wv[2].y, acc[i][1]);
                acc[i][2] = fmaf(xv[i].z, wv[2].z, acc[i][2]);
                acc[i][3] = fmaf(xv[i].z, wv[2].w, acc[i][3]);
                acc[i][0] = fmaf(xv[i].w, wv[3].x, acc[i][0]);
                acc[i][1] = fmaf(xv[i].w, wv[3].y, acc[i][1]);
                acc[i][2] = fmaf(xv[i].w, wv[3].z, acc[i][2]);
                acc[i][3] = fmaf(xv[i].w, wv[3].w, acc[i][3]);
            }
        }
    }
#pragma unroll
    for (int i = 0; i < 4; i++) {
        int row = node0 + r4 + i;
        if (row < N) {
            ushort4 ob;
            ob.x = f2bf(fmaxf(acc[i][0] + bs[c4 + 0], 0.0f));
            ob.y = f2bf(fmaxf(acc[i][1] + bs[c4 + 1], 0.0f));
            ob.z = f2bf(fmaxf(acc[i][2] + bs[c4 + 2], 0.0f));
            ob.w = f2bf(fmaxf(acc[i][3] + bs[c4 + 3], 0.0f));
            *(ushort4*)&Yb[(size_t)row * 64 + c4] = ob;
        }
    }
}

// ---------- MLP head: out = relu(Hb@Wm1+bm1) @ Wm2 + bm2 (fp32 out) ----------
__global__ __launch_bounds__(256) void k_mlp_gemm(
    const ushort_t* __restrict__ Hb, const float* __restrict__ Wm1,
    const float* __restrict__ bm1, const float* __restrict__ Wm2,
    const float* __restrict__ bm2, float* __restrict__ out, int N) {
    __shared__ float W1s[64][64];
    __shared__ float W2s[64][32];
    __shared__ float Hs[64][68];
    __shared__ float b1s[64];
    __shared__ float b2s[32];
    int t = threadIdx.x;
    for (int i = t; i < 64 * 16; i += 256) {
        int r = i >> 4, c = (i & 15) * 4;
        *(float4*)&W1s[r][c] = *(const float4*)&Wm1[r * 64 + c];
    }
    for (int i = t; i < 64 * 8; i += 256) {
        int r = i >> 3, c = (i & 7) * 4;
        *(float4*)&W2s[r][c] = *(const float4*)&Wm2[r * 32 + c];
    }
    if (t < 64) b1s[t] = bm1[t];
    else if (t < 96) b2s[t - 64] = bm2[t - 64];

    int node0 = blockIdx.x * 64;
    {
        int f4 = (t & 15) * 4;
        int nl0 = t >> 4;
        for (int p = 0; p < 4; p++) {
            int nl = nl0 + p * 16;
            int node = node0 + nl;
            float4 v = make_float4(0.f, 0.f, 0.f, 0.f);
            if (node < N) {
                ushort4 u = *(const ushort4*)&Hb[(size_t)node * 64 + f4];
                v = make_float4(bf2f(u.x), bf2f(u.y), bf2f(u.z), bf2f(u.w));
            }
            *(float4*)&Hs[nl][f4] = v;
        }
    }
    __syncthreads();

    float acc[4][4] = {{0}};
    int c4 = (t & 15) * 4;
    int r4 = (t >> 4) * 4;
#pragma unroll 4
    for (int k4 = 0; k4 < 64; k4 += 4) {
        float4 xv[4], wv[4];
#pragma unroll
        for (int i = 0; i < 4; i++) xv[i] = *(const float4*)&Hs[r4 + i][k4];
#pragma unroll
        for (int q = 0; q < 4; q++) wv[q] = *(const float4*)&W1s[k4 + q][c4];
#pragma unroll
        for (int i = 0; i < 4; i++) {
            acc[i][0] = fmaf(xv[i].x, wv[0].x, acc[i][0]);
            acc[i][1] = fmaf(xv[i].x, wv[0].y, acc[i][1]);
            acc[i][2] = fmaf(xv[i].x, wv[0].z, acc[i][2]);
            acc[i][3] = fmaf(xv[i].x, wv[0].w, acc[i][3]);
            acc[i][0] = fmaf(xv[i].y, wv[1].x, acc[i][0]);
            acc[i][1] = fmaf(xv[i].y, wv[1].y, acc[i][1]);
            acc[i][2] = fmaf(xv[i].y, wv[1].z, acc[i][2]);
            acc[i][3] = fmaf(xv[i].y, wv[1].w, acc[i][3]);
            acc[i][0] = fmaf(xv[i].z, wv[2].x, acc[i][0]);
            acc[i][1] = fmaf(xv[i].z, wv[2].y, acc[i][1]);
            acc[i][2] = fmaf(xv[i].z, wv[2].z, acc[i][2]);
            acc[i][3] = fmaf(xv[i].z, wv[2].w, acc[i][3]);
            acc[i][0] = fmaf(xv[i].w, wv[3].x, acc[i][0]);
            acc[i][1] = fmaf(xv[i].w, wv[3].y, acc[i][1]);
            acc[i][2] = fmaf(xv[i].w, wv[3].z, acc[i][2]);
            acc[i][3] = fmaf(xv[i].w, wv[3].w, acc[i][3]);
        }
    }
    __syncthreads();
#pragma unroll
    for (int i = 0; i < 4; i++) {
        float4 o;
        o.x = fmaxf(acc[i][0] + b1s[c4 + 0], 0.0f);
        o.y = fmaxf(acc[i][1] + b1s[c4 + 1], 0.0f);
        o.z = fmaxf(acc[i][2] + b1s[c4 + 2], 0.0f);
        o.w = fmaxf(acc[i][3] + b1s[c4 + 3], 0.0f);
        *(float4*)&Hs[r4 + i][c4] = o;
    }
    __syncthreads();

    {
        int cc4 = (t & 7) * 4;
        int r2 = (t >> 3) * 2;
        float a2[2][4] = {{0}};
#pragma unroll 4
        for (int k4 = 0; k4 < 64; k4 += 4) {
            float4 xv[2], wv[4];
#pragma unroll
            for (int i = 0; i < 2; i++) xv[i] = *(const float4*)&Hs[r2 + i][k4];
#pragma unroll
            for (int q = 0; q < 4; q++) wv[q] = *(const float4*)&W2s[k4 + q][cc4];
#pragma unroll
            for (int i = 0; i < 2; i++) {
                a2[i][0] = fmaf(xv[i].x, wv[0].x, a2[i][0]);
                a2[i][1] = fmaf(xv[i].x, wv[0].y, a2[i][1]);
                a2[i][2] = fmaf(xv[i].x, wv[0].z, a2[i][2]);
                a2[i][3] = fmaf(xv[i].x, wv[0].w, a2[i][3]);
                a2[i][0] = fmaf(xv[i].y, wv[1].x, a2[i][0]);
                a2[i][1] = fmaf(xv[i].y, wv[1].y, a2[i][1]);
                a2[i][2] = fmaf(xv[i].y, wv[1].z, a2[i][2]);
                a2[i][3] = fmaf(xv[i].y, wv[1].w, a2[i][3]);
                a2[i][0] = fmaf(xv[i].z, wv[2].x, a2[i][0]);
                a2[i][1] = fmaf(xv[i].z, wv[2].y, a2[i][1]);
                a2[i][2] = fmaf(xv[i].z, wv[2].z, a2[i][2]);
                a2[i][3] = fmaf(xv[i].z, wv[2].w, a2[i][3]);
                a2[i][0] = fmaf(xv[i].w, wv[3].x, a2[i][0]);
                a2[i][1] = fmaf(xv[i].w, wv[3].y, a2[i][1]);
                a2[i][2] = fmaf(xv[i].w, wv[3].z, a2[i][2]);
                a2[i][3] = fmaf(xv[i].w, wv[3].w, a2[i][3]);
            }
        }
#pragma unroll
        for (int i = 0; i < 2; i++) {
            int row = node0 + r2 + i;
            if (row < N) {
                float4 o;
                o.x = a2[i][0] + b2s[cc4 + 0];
                o.y = a2[i][1] + b2s[cc4 + 1];
                o.z = a2[i][2] + b2s[cc4 + 2];
                o.w = a2[i][3] + b2s[cc4 + 3];
                *(float4*)&out[(size_t)row * 32 + cc4] = o;
            }
        }
    }
}

extern "C" void kernel_launch(void* const* d_in, const int* in_sizes, int n_in,
                              void* d_out, int out_size, void* d_ws, size_t ws_size,
                              hipStream_t stream) {
    const float* features = (const float*)d_in[0];
    const int* src = (const int*)d_in[1];
    const int* dst = (const int*)d_in[2];
    const float* W1 = (const float*)d_in[4];
    const float* b1 = (const float*)d_in[5];
    const float* W2 = (const float*)d_in[6];
    const float* b2 = (const float*)d_in[7];
    const float* Wm1 = (const float*)d_in[8];
    const float* bm1 = (const float*)d_in[9];
    const float* Wm2 = (const float*)d_in[10];
    const float* bm2 = (const float*)d_in[11];
    float* out = (float*)d_out;

    int N = in_sizes[0] / 64;
    int E = in_sizes[1];

    float* ws = (float*)d_ws;
    float* dinv = ws;                        // [N]
    int* row_ptr = (int*)(dinv + N);         // [N+1]
    int* cursor = row_ptr + (N + 1);         // [N]
    int* bsum = cursor + N;                  // [1024]
    int2* cw = (int2*)(((uintptr_t)(bsum + 1024) + 7) & ~(uintptr_t)7);  // [E]
    // bf16 buffers [N*64] each
    ushort_t* Fb  = (ushort_t*)(cw + E);
    ushort_t* X1b = Fb  + (size_t)N * 64;
    ushort_t* X2b = X1b + (size_t)N * 64;
    ushort_t* H1b = X2b + (size_t)N * 64;
    ushort_t* H2b = H1b + (size_t)N * 64;

    int eblk = (E + 255) / 256;
    int nblk = (N + 255) / 256;
    int pblk = (N * 64 + 255) / 256;
    int gblk = (N + 63) / 64;
    int n4 = N * 16;
    int cblk = (n4 + 255) / 256;

    // CSR build
    hipMemsetAsync(cursor, 0, (size_t)N * sizeof(int), stream);
    k_hist<<<eblk, 256, 0, stream>>>(dst, cursor, E);
    k_blocksum<<<nblk, 256, 0, stream>>>(cursor, bsum, N);
    k_scanbsum<<<1, 1024, 0, stream>>>(bsum, nblk);
    k_scanfinal<<<nblk, 256, 0, stream>>>(cursor, bsum, row_ptr, cursor, dinv, N, E);
    k_place<<<eblk, 256, 0, stream>>>(src, dst, dinv, cursor, cw, E);

    // bf16 shadow of features
    k_tobf16<<<cblk, 256, 0, stream>>>((const float4*)features, (ushort4*)Fb, n4);

    // layer 1
    k_prop<1><<<pblk, 256, 0, stream>>>(Fb, row_ptr, cw, dinv, nullptr, X1b, N);
    k_prop<2><<<pblk, 256, 0, stream>>>(X1b, row_ptr, cw, dinv, Fb, X2b, N);
    k_cheb_gemm<<<gblk, 256, 0, stream>>>(Fb, X1b, X2b, W1, b1, H1b, N);

    // layer 2
    k_prop<1><<<pblk, 256, 0, stream>>>(H1b, row_ptr, cw, dinv, nullptr, X1b, N);
    k_prop<2><<<pblk, 256, 0, stream>>>(X1b, row_ptr, cw, dinv, H1b, X2b, N);
    k_cheb_gemm<<<gblk, 256, 0, stream>>>(H1b, X1b, X2b, W2, b2, H2b, N);

    // MLP head
    k_mlp_gemm<<<gblk, 256, 0, stream>>>(H2b, Wm1, bm1, Wm2, bm2, out, N);
}

// Round 9
// 429.129 us; speedup vs baseline: 1.5942x; 1.1379x over previous
//
#include <hip/hip_runtime.h>

// ChebNet round 9: line-local two-level counting sort (per-block reservation,
// no per-edge global atomics), src-only CSR col[], pre-scaled bf16 shadows
// (shadow[node] = bf16(x[node]*dinv[node])) so prop needs no per-edge weight.
// fp32 accumulate everywhere; GEMMs unscale via 1/dinv at tile staging.

typedef unsigned short ushort_t;

__device__ inline ushort_t f2bf(float f) {  // RNE float->bf16
    unsigned u = __float_as_uint(f);
    return (ushort_t)((u + 0x7FFFu + ((u >> 16) & 1u)) >> 16);
}
__device__ inline float bf2f(ushort_t h) {
    return __uint_as_float(((unsigned)h) << 16);
}

#define BSH 9               // bucket = 512 consecutive dst nodes
#define BSZ (1 << BSH)
#define CHUNK 4096          // edges per k_bucket2 block

// ---------- stage 1: global bucket histogram ----------
__global__ __launch_bounds__(256) void k_bhist(const int* __restrict__ dst,
                                               int* __restrict__ gbase, int E, int NB) {
    __shared__ int h[1024];
    for (int i = threadIdx.x; i < NB; i += 256) h[i] = 0;
    __syncthreads();
    for (int i = blockIdx.x * blockDim.x + threadIdx.x; i < E; i += gridDim.x * blockDim.x)
        atomicAdd(&h[dst[i] >> BSH], 1);
    __syncthreads();
    for (int i = threadIdx.x; i < NB; i += 256)
        if (h[i]) atomicAdd(&gbase[i], h[i]);
}

// ---------- stage 2: scan bucket counts -> gbase (excl) and gcur ----------
__global__ void k_bscan(int* __restrict__ gbase, int* __restrict__ gcur, int NB) {
    __shared__ int sh[1024];
    int t = threadIdx.x;
    int v = (t < NB) ? gbase[t] : 0;
    sh[t] = v;
    __syncthreads();
    for (int off = 1; off < 1024; off <<= 1) {
        int u = 0;
        if (t >= off) u = sh[t - off];
        __syncthreads();
        sh[t] += u;
        __syncthreads();
    }
    if (t < NB) {
        int excl = sh[t] - v;
        gbase[t] = excl;
        gcur[t] = excl;
    }
}

// ---------- stage 3: scatter edges into bucket regions ----------
// Per block: stage CHUNK edges in LDS, LDS histogram, ONE global atomic per
// (block,bucket) to reserve contiguous space, then write line-local.
__global__ __launch_bounds__(256) void k_bucket2(
    const int* __restrict__ src, const int* __restrict__ dst,
    int* __restrict__ gcur, int2* __restrict__ eb, int E, int NB) {
    __shared__ int ls[CHUNK];
    __shared__ int ld[CHUNK];
    __shared__ int hist[1024];
    __shared__ int bbase[1024];
    int t = threadIdx.x;
    int base = blockIdx.x * CHUNK;
    int count = E - base;
    if (count > CHUNK) count = CHUNK;
    for (int i = t; i < NB; i += 256) hist[i] = 0;
    __syncthreads();
    for (int i = t; i < count; i += 256) {
        int s = src[base + i];
        int d = dst[base + i];
        ls[i] = s;
        ld[i] = d;
        atomicAdd(&hist[d >> BSH], 1);
    }
    __syncthreads();
    for (int b = t; b < NB; b += 256) {
        int c = hist[b];
        bbase[b] = c ? atomicAdd(&gcur[b], c) : 0;
        hist[b] = 0;  // reuse as local cursor
    }
    __syncthreads();
    for (int i = t; i < count; i += 256) {
        int d = ld[i];
        int b = d >> BSH;
        int off = atomicAdd(&hist[b], 1);
        eb[bbase[b] + off] = make_int2(ls[i], d);
    }
}

// ---------- stage 4: per-bucket finalize ----------
// counts per dst, LDS scan -> row_ptr slice + dinv + final col[] placement.
__global__ __launch_bounds__(256) void k_local(
    const int2* __restrict__ eb, const int* __restrict__ gbase,
    int* __restrict__ col, int* __restrict__ row_ptr,
    float* __restrict__ dinv, int N, int E, int NB) {
    __shared__ int cnt[BSZ];
    __shared__ int tsum[256];
    int t = threadIdx.x;
    int b = blockIdx.x;
    int d0 = b << BSH;
    cnt[2 * t] = 0;
    cnt[2 * t + 1] = 0;
    __syncthreads();
    int beg = gbase[b];
    int end = (b + 1 < NB) ? gbase[b + 1] : E;
    for (int i = beg + t; i < end; i += 256)
        atomicAdd(&cnt[eb[i].y - d0], 1);
    __syncthreads();
    int c0 = cnt[2 * t], c1 = cnt[2 * t + 1];
    int mysum = c0 + c1;
    tsum[t] = mysum;
    __syncthreads();
    for (int off = 1; off < 256; off <<= 1) {
        int u = 0;
        if (t >= off) u = tsum[t - off];
        __syncthreads();
        tsum[t] += u;
        __syncthreads();
    }
    int rbase = beg + tsum[t] - mysum;  // exclusive prefix
    int d = d0 + 2 * t;
    if (d < N) {
        row_ptr[d] = rbase;
        dinv[d] = rsqrtf(fmaxf((float)c0, 1.0f));
    }
    if (d + 1 < N) {
        row_ptr[d + 1] = rbase + c0;
        dinv[d + 1] = rsqrtf(fmaxf((float)c1, 1.0f));
    }
    cnt[2 * t] = rbase;          // reuse as cursors
    cnt[2 * t + 1] = rbase + c0;
    __syncthreads();
    for (int i = beg + t; i < end; i += 256) {
        int2 e = eb[i];
        int p = atomicAdd(&cnt[e.y - d0], 1);
        col[p] = e.x;
    }
    if (b == NB - 1 && t == 0) row_ptr[N] = E;
}

// ---------- fp32 -> scaled bf16 shadow: Fb = bf16(features*dinv) ----------
__global__ void k_tobf16(const float4* __restrict__ X, const float* __restrict__ dinv,
                         ushort4* __restrict__ Y, int n4) {
    int i = blockIdx.x * blockDim.x + threadIdx.x;
    if (i < n4) {
        float s = dinv[i >> 4];
        float4 v = X[i];
        ushort4 o;
        o.x = f2bf(v.x * s); o.y = f2bf(v.y * s); o.z = f2bf(v.z * s); o.w = f2bf(v.w * s);
        Y[i] = o;
    }
}

// ---------- propagation: gather pre-scaled rows, plain sum ----------
// MODE 1: OUTB = bf16(-di*di*S)          (scaled output, feeds next gather)
// MODE 2: OUTB = bf16(-2*di*S - X0)      (unscaled; X0 = X0b_scaled/di)
template <int MODE>
__global__ __launch_bounds__(256) void k_prop(
    const ushort_t* __restrict__ Xb, const int* __restrict__ rp,
    const int* __restrict__ col, const float* __restrict__ dinv,
    const ushort_t* __restrict__ X0b, ushort_t* __restrict__ OUTB, int N) {
    int wid = (blockIdx.x * blockDim.x + threadIdx.x) >> 6;
    int lane = threadIdx.x & 63;
    if (wid >= N) return;
    int g = lane >> 4;
    int fl = (lane & 15) * 4;
    int beg = rp[wid], end = rp[wid + 1];
    float4 a0 = make_float4(0.f, 0.f, 0.f, 0.f);
    float4 a1 = make_float4(0.f, 0.f, 0.f, 0.f);
    int e = beg + g;
    for (; e + 4 < end; e += 8) {
        int s0 = col[e], s1 = col[e + 4];
        ushort4 u0 = *(const ushort4*)&Xb[(size_t)s0 * 64 + fl];
        ushort4 u1 = *(const ushort4*)&Xb[(size_t)s1 * 64 + fl];
        a0.x += bf2f(u0.x); a0.y += bf2f(u0.y); a0.z += bf2f(u0.z); a0.w += bf2f(u0.w);
        a1.x += bf2f(u1.x); a1.y += bf2f(u1.y); a1.z += bf2f(u1.z); a1.w += bf2f(u1.w);
    }
    if (e < end) {
        int s0 = col[e];
        ushort4 u0 = *(const ushort4*)&Xb[(size_t)s0 * 64 + fl];
        a0.x += bf2f(u0.x); a0.y += bf2f(u0.y); a0.z += bf2f(u0.z); a0.w += bf2f(u0.w);
    }
    float4 acc;
    acc.x = a0.x + a1.x;
    acc.y = a0.y + a1.y;
    acc.z = a0.z + a1.z;
    acc.w = a0.w + a1.w;
    acc.x += __shfl_xor(acc.x, 16);
    acc.y += __shfl_xor(acc.y, 16);
    acc.z += __shfl_xor(acc.z, 16);
    acc.w += __shfl_xor(acc.w, 16);
    acc.x += __shfl_xor(acc.x, 32);
    acc.y += __shfl_xor(acc.y, 32);
    acc.z += __shfl_xor(acc.z, 32);
    acc.w += __shfl_xor(acc.w, 32);
    if (g == 0) {
        float di = dinv[wid];
        float4 o;
        if (MODE == 1) {
            float m = -di * di;
            o.x = m * acc.x; o.y = m * acc.y; o.z = m * acc.z; o.w = m * acc.w;
        } else {
            ushort4 x0u = *(const ushort4*)&X0b[(size_t)wid * 64 + fl];
            float m = -2.0f * di;
            float rd = 1.0f / di;
            o.x = fmaf(m, acc.x, -rd * bf2f(x0u.x));
            o.y = fmaf(m, acc.y, -rd * bf2f(x0u.y));
            o.z = fmaf(m, acc.z, -rd * bf2f(x0u.z));
            o.w = fmaf(m, acc.w, -rd * bf2f(x0u.w));
        }
        ushort4 ob;
        ob.x = f2bf(o.x); ob.y = f2bf(o.y); ob.z = f2bf(o.z); ob.w = f2bf(o.w);
        *(ushort4*)&OUTB[(size_t)wid * 64 + fl] = ob;
    }
}

// ---------- cheb linear: Yb = relu([X0|X1|X2] @ W + b) ----------
// X0,X1 scaled (unscale by 1/dinv at staging), X2 unscaled.
// SCALE_OUT: write bf16(y*dinv) (feeds gathers) else bf16(y).
template <bool SCALE_OUT>
__global__ __launch_bounds__(256) void k_cheb_gemm(
    const ushort_t* __restrict__ X0, const ushort_t* __restrict__ X1,
    const ushort_t* __restrict__ X2, const float* __restrict__ dinv,
    const float* __restrict__ W, const float* __restrict__ b,
    ushort_t* __restrict__ Yb, int N) {
    __shared__ float Ws[64][64];
    __shared__ float Xs[64][68];
    __shared__ float bs[64];
    int t = threadIdx.x;
    if (t < 64) bs[t] = b[t];

    int c4 = (t & 15) * 4;
    int r4 = (t >> 4) * 4;
    int node0 = blockIdx.x * 64;
    float acc[4][4] = {{0}};

    const ushort_t* Xp[3] = {X0, X1, X2};
#pragma unroll 1
    for (int chunk = 0; chunk < 3; chunk++) {
        __syncthreads();
        {
            const float* Wc = W + chunk * 64 * 64;
            for (int i = t; i < 64 * 16; i += 256) {
                int r = i >> 4, c = (i & 15) * 4;
                *(float4*)&Ws[r][c] = *(const float4*)&Wc[r * 64 + c];
            }
        }
        {
            const ushort_t* X = Xp[chunk];
            bool unscale = (chunk < 2);
            int f4 = (t & 15) * 4;
            int nl0 = t >> 4;
            for (int p = 0; p < 4; p++) {
                int nl = nl0 + p * 16;
                int node = node0 + nl;
                float4 v = make_float4(0.f, 0.f, 0.f, 0.f);
                if (node < N) {
                    ushort4 u = *(const ushort4*)&X[(size_t)node * 64 + f4];
                    float r = unscale ? (1.0f / dinv[node]) : 1.0f;
                    v = make_float4(r * bf2f(u.x), r * bf2f(u.y),
                                    r * bf2f(u.z), r * bf2f(u.w));
                }
                *(float4*)&Xs[nl][f4] = v;
            }
        }
        __syncthreads();
#pragma unroll 4
        for (int k4 = 0; k4 < 64; k4 += 4) {
            float4 xv[4], wv[4];
#pragma unroll
            for (int i = 0; i < 4; i++) xv[i] = *(const float4*)&Xs[r4 + i][k4];
#pragma unroll
            for (int q = 0; q < 4; q++) wv[q] = *(const float4*)&Ws[k4 + q][c4];
#pragma unroll
            for (int i = 0; i < 4; i++) {
                acc[i][0] = fmaf(xv[i].x, wv[0].x, acc[i][0]);
                acc[i][1] = fmaf(xv[i].x, wv[0].y, acc[i][1]);
                acc[i][2] = fmaf(xv[i].x, wv[0].z, acc[i][2]);
                acc[i][3] = fmaf(xv[i].x, wv[0].w, acc[i][3]);
                acc[i][0] = fmaf(xv[i].y, wv[1].x, acc[i][0]);
                acc[i][1] = fmaf(xv[i].y, wv[1].y, acc[i][1]);
                acc[i][2] = fmaf(xv[i].y, wv[1].z, acc[i][2]);
                acc[i][3] = fmaf(xv[i].y, wv[1].w, acc[i][3]);
                acc[i][0] = fmaf(xv[i].z, wv[2].x, acc[i][0]);
                acc[i][1] = fmaf(xv[i].z, wv[2].y, acc[i][1]);
                acc[i][2] = fmaf(xv[i].z, wv[2].z, acc[i][2]);
                acc[i][3] = fmaf(xv[i].z, wv[2].w, acc[i][3]);
                acc[i][0] = fmaf(xv[i].w, wv[3].x, acc[i][0]);
                acc[i][1] = fmaf(xv[i].w, wv[3].y, acc[i][1]);
                acc[i][2] = fmaf(xv[i].w, wv[3].z, acc[i][2]);
                acc[i][3] = fmaf(xv[i].w, wv[3].w, acc[i][3]);
            }
        }
    }
#pragma unroll
    for (int i = 0; i < 4; i++) {
        int row = node0 + r4 + i;
        if (row < N) {
            float s = SCALE_OUT ? dinv[row] : 1.0f;
            ushort4 ob;
            ob.x = f2bf(s * fmaxf(acc[i][0] + bs[c4 + 0], 0.0f));
            ob.y = f2bf(s * fmaxf(acc[i][1] + bs[c4 + 1], 0.0f));
            ob.z = f2bf(s * fmaxf(acc[i][2] + bs[c4 + 2], 0.0f));
            ob.w = f2bf(s * fmaxf(acc[i][3] + bs[c4 + 3], 0.0f));
            *(ushort4*)&Yb[(size_t)row * 64 + c4] = ob;
        }
    }
}

// ---------- MLP head: out = relu(Hb@Wm1+bm1) @ Wm2 + bm2 (Hb unscaled) ----------
__global__ __launch_bounds__(256) void k_mlp_gemm(
    const ushort_t* __restrict__ Hb, const float* __restrict__ Wm1,
    const float* __restrict__ bm1, const float* __restrict__ Wm2,
    const float* __restrict__ bm2, float* __restrict__ out, int N) {
    __shared__ float W1s[64][64];
    __shared__ float W2s[64][32];
    __shared__ float Hs[64][68];
    __shared__ float b1s[64];
    __shared__ float b2s[32];
    int t = threadIdx.x;
    for (int i = t; i < 64 * 16; i += 256) {
        int r = i >> 4, c = (i & 15) * 4;
        *(float4*)&W1s[r][c] = *(const float4*)&Wm1[r * 64 + c];
    }
    for (int i = t; i < 64 * 8; i += 256) {
        int r = i >> 3, c = (i & 7) * 4;
        *(float4*)&W2s[r][c] = *(const float4*)&Wm2[r * 32 + c];
    }
    if (t < 64) b1s[t] = bm1[t];
    else if (t < 96) b2s[t - 64] = bm2[t - 64];

    int node0 = blockIdx.x * 64;
    {
        int f4 = (t & 15) * 4;
        int nl0 = t >> 4;
        for (int p = 0; p < 4; p++) {
            int nl = nl0 + p * 16;
            int node = node0 + nl;
            float4 v = make_float4(0.f, 0.f, 0.f, 0.f);
            if (node < N) {
                ushort4 u = *(const ushort4*)&Hb[(size_t)node * 64 + f4];
                v = make_float4(bf2f(u.x), bf2f(u.y), bf2f(u.z), bf2f(u.w));
            }
            *(float4*)&Hs[nl][f4] = v;
        }
    }
    __syncthreads();

    float acc[4][4] = {{0}};
    int c4 = (t & 15) * 4;
    int r4 = (t >> 4) * 4;
#pragma unroll 4
    for (int k4 = 0; k4 < 64; k4 += 4) {
        float4 xv[4], wv[4];
#pragma unroll
        for (int i = 0; i < 4; i++) xv[i] = *(const float4*)&Hs[r4 + i][k4];
#pragma unroll
        for (int q = 0; q < 4; q++) wv[q] = *(const float4*)&W1s[k4 + q][c4];
#pragma unroll
        for (int i = 0; i < 4; i++) {
            acc[i][0] = fmaf(xv[i].x, wv[0].x, acc[i][0]);
            acc[i][1] = fmaf(xv[i].x, wv[0].y, acc[i][1]);
            acc[i][2] = fmaf(xv[i].x, wv[0].z, acc[i][2]);
            acc[i][3] = fmaf(xv[i].x, wv[0].w, acc[i][3]);
            acc[i][0] = fmaf(xv[i].y, wv[1].x, acc[i][0]);
            acc[i][1] = fmaf(xv[i].y, wv[1].y, acc[i][1]);
            acc[i][2] = fmaf(xv[i].y, wv[1].z, acc[i][2]);
            acc[i][3] = fmaf(xv[i].y, wv[1].w, acc[i][3]);
            acc[i][0] = fmaf(xv[i].z, wv[2].x, acc[i][0]);
            acc[i][1] = fmaf(xv[i].z, wv[2].y, acc[i][1]);
            acc[i][2] = fmaf(xv[i].z, wv[2].z, acc[i][2]);
            acc[i][3] = fmaf(xv[i].z, wv[2].w, acc[i][3]);
            acc[i][0] = fmaf(xv[i].w, wv[3].x, acc[i][0]);
            acc[i][1] = fmaf(xv[i].w, wv[3].y, acc[i][1]);
            acc[i][2] = fmaf(xv[i].w, wv[3].z, acc[i][2]);
            acc[i][3] = fmaf(xv[i].w, wv[3].w, acc[i][3]);
        }
    }
    __syncthreads();
#pragma unroll
    for (int i = 0; i < 4; i++) {
        float4 o;
        o.x = fmaxf(acc[i][0] + b1s[c4 + 0], 0.0f);
        o.y = fmaxf(acc[i][1] + b1s[c4 + 1], 0.0f);
        o.z = fmaxf(acc[i][2] + b1s[c4 + 2], 0.0f);
        o.w = fmaxf(acc[i][3] + b1s[c4 + 3], 0.0f);
        *(float4*)&Hs[r4 + i][c4] = o;
    }
    __syncthreads();

    {
        int cc4 = (t & 7) * 4;
        int r2 = (t >> 3) * 2;
        float a2[2][4] = {{0}};
#pragma unroll 4
        for (int k4 = 0; k4 < 64; k4 += 4) {
            float4 xv[2], wv[4];
#pragma unroll
            for (int i = 0; i < 2; i++) xv[i] = *(const float4*)&Hs[r2 + i][k4];
#pragma unroll
            for (int q = 0; q < 4; q++) wv[q] = *(const float4*)&W2s[k4 + q][cc4];
#pragma unroll
            for (int i = 0; i < 2; i++) {
                a2[i][0] = fmaf(xv[i].x, wv[0].x, a2[i][0]);
                a2[i][1] = fmaf(xv[i].x, wv[0].y, a2[i][1]);
                a2[i][2] = fmaf(xv[i].x, wv[0].z, a2[i][2]);
                a2[i][3] = fmaf(xv[i].x, wv[0].w, a2[i][3]);
                a2[i][0] = fmaf(xv[i].y, wv[1].x, a2[i][0]);
                a2[i][1] = fmaf(xv[i].y, wv[1].y, a2[i][1]);
                a2[i][2] = fmaf(xv[i].y, wv[1].z, a2[i][2]);
                a2[i][3] = fmaf(xv[i].y, wv[1].w, a2[i][3]);
                a2[i][0] = fmaf(xv[i].z, wv[2].x, a2[i][0]);
                a2[i][1] = fmaf(xv[i].z, wv[2].y, a2[i][1]);
                a2[i][2] = fmaf(xv[i].z, wv[2].z, a2[i][2]);
                a2[i][3] = fmaf(xv[i].z, wv[2].w, a2[i][3]);
                a2[i][0] = fmaf(xv[i].w, wv[3].x, a2[i][0]);
                a2[i][1] = fmaf(xv[i].w, wv[3].y, a2[i][1]);
                a2[i][2] = fmaf(xv[i].w, wv[3].z, a2[i][2]);
                a2[i][3] = fmaf(xv[i].w, wv[3].w, a2[i][3]);
            }
        }
#pragma unroll
        for (int i = 0; i < 2; i++) {
            int row = node0 + r2 + i;
            if (row < N) {
                float4 o;
                o.x = a2[i][0] + b2s[cc4 + 0];
                o.y = a2[i][1] + b2s[cc4 + 1];
                o.z = a2[i][2] + b2s[cc4 + 2];
                o.w = a2[i][3] + b2s[cc4 + 3];
                *(float4*)&out[(size_t)row * 32 + cc4] = o;
            }
        }
    }
}

extern "C" void kernel_launch(void* const* d_in, const int* in_sizes, int n_in,
                              void* d_out, int out_size, void* d_ws, size_t ws_size,
                              hipStream_t stream) {
    const float* features = (const float*)d_in[0];
    const int* src = (const int*)d_in[1];
    const int* dst = (const int*)d_in[2];
    const float* W1 = (const float*)d_in[4];
    const float* b1 = (const float*)d_in[5];
    const float* W2 = (const float*)d_in[6];
    const float* b2 = (const float*)d_in[7];
    const float* Wm1 = (const float*)d_in[8];
    const float* bm1 = (const float*)d_in[9];
    const float* Wm2 = (const float*)d_in[10];
    const float* bm2 = (const float*)d_in[11];
    float* out = (float*)d_out;

    int N = in_sizes[0] / 64;
    int E = in_sizes[1];
    int NB = (N + BSZ - 1) >> BSH;  // dst buckets of 512

    float* ws = (float*)d_ws;
    float* dinv = ws;                           // [N]
    int* row_ptr = (int*)(dinv + N);            // [N+1]
    int* gbase = row_ptr + (N + 1);             // [1024]
    int* gcur = gbase + 1024;                   // [1024]
    int* col = gcur + 1024;                     // [E]
    int2* eb = (int2*)(((uintptr_t)(col + E) + 7) & ~(uintptr_t)7);  // [E]
    ushort_t* Fb  = (ushort_t*)(eb + E);        // [N*64] scaled
    ushort_t* X1b = Fb  + (size_t)N * 64;       // scaled
    ushort_t* X2b = X1b + (size_t)N * 64;       // unscaled
    ushort_t* H1b = X2b + (size_t)N * 64;       // scaled
    ushort_t* H2b = H1b + (size_t)N * 64;       // unscaled

    int pblk = (N * 64 + 255) / 256;
    int gblk = (N + 63) / 64;
    int n4 = N * 16;
    int cblk = (n4 + 255) / 256;
    int bblk = (E + CHUNK - 1) / CHUNK;

    // ---- CSR build: bucket histogram -> scan -> scatter -> finalize ----
    hipMemsetAsync(gbase, 0, NB * sizeof(int), stream);
    k_bhist<<<512, 256, 0, stream>>>(dst, gbase, E, NB);
    k_bscan<<<1, 1024, 0, stream>>>(gbase, gcur, NB);
    k_bucket2<<<bblk, 256, 0, stream>>>(src, dst, gcur, eb, E, NB);
    k_local<<<NB, 256, 0, stream>>>(eb, gbase, col, row_ptr, dinv, N, E, NB);

    // scaled bf16 shadow of features
    k_tobf16<<<cblk, 256, 0, stream>>>((const float4*)features, dinv, (ushort4*)Fb, n4);

    // layer 1
    k_prop<1><<<pblk, 256, 0, stream>>>(Fb, row_ptr, col, dinv, nullptr, X1b, N);
    k_prop<2><<<pblk, 256, 0, stream>>>(X1b, row_ptr, col, dinv, Fb, X2b, N);
    k_cheb_gemm<true><<<gblk, 256, 0, stream>>>(Fb, X1b, X2b, dinv, W1, b1, H1b, N);

    // layer 2
    k_prop<1><<<pblk, 256, 0, stream>>>(H1b, row_ptr, col, dinv, nullptr, X1b, N);
    k_prop<2><<<pblk, 256, 0, stream>>>(X1b, row_ptr, col, dinv, H1b, X2b, N);
    k_cheb_gemm<false><<<gblk, 256, 0, stream>>>(H1b, X1b, X2b, dinv, W2, b2, H2b, N);

    // MLP head
    k_mlp_gemm<<<gblk, 256, 0, stream>>>(H2b, Wm1, bm1, Wm2, bm2, out, N);
}

// Round 10
// 395.878 us; speedup vs baseline: 1.7281x; 1.0840x over previous
//
#include <hip/hip_runtime.h>

// ChebNet round 10: MFMA (16x16x32 bf16) for all dense GEMMs, A-fragments
// direct from global bf16, B from bf16-transposed weights (k_wprep).
// dinv un-scaling folded into MFMA epilogue (scaled/unscaled acc split).
// CSR build + props unchanged from R9.

typedef unsigned short ushort_t;
typedef __attribute__((ext_vector_type(8))) short v8s;
typedef __attribute__((ext_vector_type(4))) float v4f;

__device__ inline ushort_t f2bf(float f) {  // RNE float->bf16
    unsigned u = __float_as_uint(f);
    return (ushort_t)((u + 0x7FFFu + ((u >> 16) & 1u)) >> 16);
}
__device__ inline float bf2f(ushort_t h) {
    return __uint_as_float(((unsigned)h) << 16);
}

#define BSH 9
#define BSZ (1 << BSH)
#define CHUNK 4096

// ---------- CSR build (R9) ----------

__global__ __launch_bounds__(256) void k_bhist(const int* __restrict__ dst,
                                               int* __restrict__ gbase, int E, int NB) {
    __shared__ int h[1024];
    for (int i = threadIdx.x; i < NB; i += 256) h[i] = 0;
    __syncthreads();
    for (int i = blockIdx.x * blockDim.x + threadIdx.x; i < E; i += gridDim.x * blockDim.x)
        atomicAdd(&h[dst[i] >> BSH], 1);
    __syncthreads();
    for (int i = threadIdx.x; i < NB; i += 256)
        if (h[i]) atomicAdd(&gbase[i], h[i]);
}

__global__ void k_bscan(int* __restrict__ gbase, int* __restrict__ gcur, int NB) {
    __shared__ int sh[1024];
    int t = threadIdx.x;
    int v = (t < NB) ? gbase[t] : 0;
    sh[t] = v;
    __syncthreads();
    for (int off = 1; off < 1024; off <<= 1) {
        int u = 0;
        if (t >= off) u = sh[t - off];
        __syncthreads();
        sh[t] += u;
        __syncthreads();
    }
    if (t < NB) {
        int excl = sh[t] - v;
        gbase[t] = excl;
        gcur[t] = excl;
    }
}

__global__ __launch_bounds__(256) void k_bucket2(
    const int* __restrict__ src, const int* __restrict__ dst,
    int* __restrict__ gcur, int2* __restrict__ eb, int E, int NB) {
    __shared__ int ls[CHUNK];
    __shared__ int ld[CHUNK];
    __shared__ int hist[1024];
    __shared__ int bbase[1024];
    int t = threadIdx.x;
    int base = blockIdx.x * CHUNK;
    int count = E - base;
    if (count > CHUNK) count = CHUNK;
    for (int i = t; i < NB; i += 256) hist[i] = 0;
    __syncthreads();
    for (int i = t; i < count; i += 256) {
        int s = src[base + i];
        int d = dst[base + i];
        ls[i] = s;
        ld[i] = d;
        atomicAdd(&hist[d >> BSH], 1);
    }
    __syncthreads();
    for (int b = t; b < NB; b += 256) {
        int c = hist[b];
        bbase[b] = c ? atomicAdd(&gcur[b], c) : 0;
        hist[b] = 0;
    }
    __syncthreads();
    for (int i = t; i < count; i += 256) {
        int d = ld[i];
        int b = d >> BSH;
        int off = atomicAdd(&hist[b], 1);
        eb[bbase[b] + off] = make_int2(ls[i], d);
    }
}

__global__ __launch_bounds__(256) void k_local(
    const int2* __restrict__ eb, const int* __restrict__ gbase,
    int* __restrict__ col, int* __restrict__ row_ptr,
    float* __restrict__ dinv, int N, int E, int NB) {
    __shared__ int cnt[BSZ];
    __shared__ int tsum[256];
    int t = threadIdx.x;
    int b = blockIdx.x;
    int d0 = b << BSH;
    cnt[2 * t] = 0;
    cnt[2 * t + 1] = 0;
    __syncthreads();
    int beg = gbase[b];
    int end = (b + 1 < NB) ? gbase[b + 1] : E;
    for (int i = beg + t; i < end; i += 256)
        atomicAdd(&cnt[eb[i].y - d0], 1);
    __syncthreads();
    int c0 = cnt[2 * t], c1 = cnt[2 * t + 1];
    int mysum = c0 + c1;
    tsum[t] = mysum;
    __syncthreads();
    for (int off = 1; off < 256; off <<= 1) {
        int u = 0;
        if (t >= off) u = tsum[t - off];
        __syncthreads();
        tsum[t] += u;
        __syncthreads();
    }
    int rbase = beg + tsum[t] - mysum;
    int d = d0 + 2 * t;
    if (d < N) {
        row_ptr[d] = rbase;
        dinv[d] = rsqrtf(fmaxf((float)c0, 1.0f));
    }
    if (d + 1 < N) {
        row_ptr[d + 1] = rbase + c0;
        dinv[d + 1] = rsqrtf(fmaxf((float)c1, 1.0f));
    }
    cnt[2 * t] = rbase;
    cnt[2 * t + 1] = rbase + c0;
    __syncthreads();
    for (int i = beg + t; i < end; i += 256) {
        int2 e = eb[i];
        int p = atomicAdd(&cnt[e.y - d0], 1);
        col[p] = e.x;
    }
    if (b == NB - 1 && t == 0) row_ptr[N] = E;
}

// ---------- weight prep: fp32 -> bf16 transposed (k-contiguous) ----------
__global__ void k_wprep(const float* __restrict__ W1, const float* __restrict__ W2,
                        const float* __restrict__ Wm1, const float* __restrict__ Wm2,
                        ushort_t* __restrict__ W1t, ushort_t* __restrict__ W2t,
                        ushort_t* __restrict__ Wm1t, ushort_t* __restrict__ Wm2t) {
    int i = blockIdx.x * 256 + threadIdx.x;
    if (i < 12288) { int k = i >> 6, n = i & 63; W1t[n * 192 + k] = f2bf(W1[i]); return; }
    i -= 12288;
    if (i < 12288) { int k = i >> 6, n = i & 63; W2t[n * 192 + k] = f2bf(W2[i]); return; }
    i -= 12288;
    if (i < 4096) { int k = i >> 6, n = i & 63; Wm1t[n * 64 + k] = f2bf(Wm1[i]); return; }
    i -= 4096;
    if (i < 2048) { int k = i >> 5, n = i & 31; Wm2t[n * 64 + k] = f2bf(Wm2[i]); }
}

// ---------- fp32 -> scaled bf16 shadow ----------
__global__ void k_tobf16(const float4* __restrict__ X, const float* __restrict__ dinv,
                         ushort4* __restrict__ Y, int n4) {
    int i = blockIdx.x * blockDim.x + threadIdx.x;
    if (i < n4) {
        float s = dinv[i >> 4];
        float4 v = X[i];
        ushort4 o;
        o.x = f2bf(v.x * s); o.y = f2bf(v.y * s); o.z = f2bf(v.z * s); o.w = f2bf(v.w * s);
        Y[i] = o;
    }
}

// ---------- propagation (R9) ----------
template <int MODE>
__global__ __launch_bounds__(256) void k_prop(
    const ushort_t* __restrict__ Xb, const int* __restrict__ rp,
    const int* __restrict__ col, const float* __restrict__ dinv,
    const ushort_t* __restrict__ X0b, ushort_t* __restrict__ OUTB, int N) {
    int wid = (blockIdx.x * blockDim.x + threadIdx.x) >> 6;
    int lane = threadIdx.x & 63;
    if (wid >= N) return;
    int g = lane >> 4;
    int fl = (lane & 15) * 4;
    int beg = rp[wid], end = rp[wid + 1];
    float4 a0 = make_float4(0.f, 0.f, 0.f, 0.f);
    float4 a1 = make_float4(0.f, 0.f, 0.f, 0.f);
    int e = beg + g;
    for (; e + 4 < end; e += 8) {
        int s0 = col[e], s1 = col[e + 4];
        ushort4 u0 = *(const ushort4*)&Xb[(size_t)s0 * 64 + fl];
        ushort4 u1 = *(const ushort4*)&Xb[(size_t)s1 * 64 + fl];
        a0.x += bf2f(u0.x); a0.y += bf2f(u0.y); a0.z += bf2f(u0.z); a0.w += bf2f(u0.w);
        a1.x += bf2f(u1.x); a1.y += bf2f(u1.y); a1.z += bf2f(u1.z); a1.w += bf2f(u1.w);
    }
    if (e < end) {
        int s0 = col[e];
        ushort4 u0 = *(const ushort4*)&Xb[(size_t)s0 * 64 + fl];
        a0.x += bf2f(u0.x); a0.y += bf2f(u0.y); a0.z += bf2f(u0.z); a0.w += bf2f(u0.w);
    }
    float4 acc;
    acc.x = a0.x + a1.x;
    acc.y = a0.y + a1.y;
    acc.z = a0.z + a1.z;
    acc.w = a0.w + a1.w;
    acc.x += __shfl_xor(acc.x, 16);
    acc.y += __shfl_xor(acc.y, 16);
    acc.z += __shfl_xor(acc.z, 16);
    acc.w += __shfl_xor(acc.w, 16);
    acc.x += __shfl_xor(acc.x, 32);
    acc.y += __shfl_xor(acc.y, 32);
    acc.z += __shfl_xor(acc.z, 32);
    acc.w += __shfl_xor(acc.w, 32);
    if (g == 0) {
        float di = dinv[wid];
        float4 o;
        if (MODE == 1) {
            float m = -di * di;
            o.x = m * acc.x; o.y = m * acc.y; o.z = m * acc.z; o.w = m * acc.w;
        } else {
            ushort4 x0u = *(const ushort4*)&X0b[(size_t)wid * 64 + fl];
            float m = -2.0f * di;
            float rd = 1.0f / di;
            o.x = fmaf(m, acc.x, -rd * bf2f(x0u.x));
            o.y = fmaf(m, acc.y, -rd * bf2f(x0u.y));
            o.z = fmaf(m, acc.z, -rd * bf2f(x0u.z));
            o.w = fmaf(m, acc.w, -rd * bf2f(x0u.w));
        }
        ushort4 ob;
        ob.x = f2bf(o.x); ob.y = f2bf(o.y); ob.z = f2bf(o.z); ob.w = f2bf(o.w);
        *(ushort4*)&OUTB[(size_t)wid * 64 + fl] = ob;
    }
}

// ---------- cheb linear via MFMA ----------
// Y[N,64] = relu([X0|X1|X2] @ W + b); X0,X1 pre-scaled by dinv (acc_s),
// X2 unscaled (acc_u); epilogue y = acc_s/dinv + acc_u + b.
// Wave w: rows [w*16,(w+1)*16), 4 col-tiles of 16. A frags from global bf16.
template <bool SCALE_OUT>
__global__ __launch_bounds__(256) void k_cheb_mfma(
    const ushort_t* __restrict__ X0, const ushort_t* __restrict__ X1,
    const ushort_t* __restrict__ X2, const float* __restrict__ dinv,
    const ushort_t* __restrict__ Wt,  // bf16 [64][192] (col-major-k)
    const float* __restrict__ b, ushort_t* __restrict__ Yb, int N) {
    int wave = threadIdx.x >> 6, lane = threadIdx.x & 63;
    int n16 = lane & 15, q = lane >> 4;
    int node0 = blockIdx.x * 64;
    int arow = node0 + wave * 16 + n16;  // A-operand row (A[m=lane&15][k=q*8+j])
    const ushort_t* Xc[3] = {X0, X1, X2};

    v4f acc_s[4], acc_u[4];
#pragma unroll
    for (int t = 0; t < 4; t++) {
        acc_s[t] = (v4f){0.f, 0.f, 0.f, 0.f};
        acc_u[t] = (v4f){0.f, 0.f, 0.f, 0.f};
    }

#pragma unroll
    for (int ks = 0; ks < 6; ks++) {
        int c = ks >> 1;
        int kk = (ks & 1) * 32 + q * 8;
        v8s av = {0, 0, 0, 0, 0, 0, 0, 0};
        if (arow < N) av = *(const v8s*)&Xc[c][(size_t)arow * 64 + kk];
#pragma unroll
        for (int t = 0; t < 4; t++) {
            v8s bv = *(const v8s*)&Wt[(size_t)(t * 16 + n16) * 192 + ks * 32 + q * 8];
            if (c < 2)
                acc_s[t] = __builtin_amdgcn_mfma_f32_16x16x32_bf16(av, bv, acc_s[t], 0, 0, 0);
            else
                acc_u[t] = __builtin_amdgcn_mfma_f32_16x16x32_bf16(av, bv, acc_u[t], 0, 0, 0);
        }
    }

    // C/D layout: col = t*16 + (lane&15), row = q*4 + reg
    int rbase = node0 + wave * 16 + q * 4;
#pragma unroll
    for (int r = 0; r < 4; r++) {
        int row = rbase + r;
        if (row < N) {
            float dv = dinv[row];
            float rd = 1.0f / dv;
            float s = SCALE_OUT ? dv : 1.0f;
#pragma unroll
            for (int t = 0; t < 4; t++) {
                float y = fmaf(rd, acc_s[t][r], acc_u[t][r]) + b[t * 16 + n16];
                y = fmaxf(y, 0.0f);
                Yb[(size_t)row * 64 + t * 16 + n16] = f2bf(s * y);
            }
        }
    }
}

// ---------- MLP head via MFMA ----------
// out[N,32] = relu(H@Wm1+b1) @ Wm2 + b2. Hidden round-trips LDS (bf16).
__global__ __launch_bounds__(256) void k_mlp_mfma(
    const ushort_t* __restrict__ Hb, const ushort_t* __restrict__ W1t,
    const float* __restrict__ b1, const ushort_t* __restrict__ W2t,
    const float* __restrict__ b2, float* __restrict__ out, int N) {
    __shared__ ushort_t Hs[64][76];  // pad 12 ushorts -> <=4-way banks
    int wave = threadIdx.x >> 6, lane = threadIdx.x & 63;
    int n16 = lane & 15, q = lane >> 4;
    int node0 = blockIdx.x * 64;
    int arow = node0 + wave * 16 + n16;

    v4f acc[4];
#pragma unroll
    for (int t = 0; t < 4; t++) acc[t] = (v4f){0.f, 0.f, 0.f, 0.f};
#pragma unroll
    for (int ks = 0; ks < 2; ks++) {
        v8s av = {0, 0, 0, 0, 0, 0, 0, 0};
        if (arow < N) av = *(const v8s*)&Hb[(size_t)arow * 64 + ks * 32 + q * 8];
#pragma unroll
        for (int t = 0; t < 4; t++) {
            v8s bv = *(const v8s*)&W1t[(size_t)(t * 16 + n16) * 64 + ks * 32 + q * 8];
            acc[t] = __builtin_amdgcn_mfma_f32_16x16x32_bf16(av, bv, acc[t], 0, 0, 0);
        }
    }
    // hidden = relu(acc + b1) -> LDS bf16 (C/D layout: row = q*4+r local)
    int lr = wave * 16 + q * 4;
#pragma unroll
    for (int r = 0; r < 4; r++)
#pragma unroll
        for (int t = 0; t < 4; t++) {
            float y = acc[t][r] + b1[t * 16 + n16];
            Hs[lr + r][t * 16 + n16] = f2bf(fmaxf(y, 0.0f));
        }
    __syncthreads();

    v4f a2[2];
    a2[0] = (v4f){0.f, 0.f, 0.f, 0.f};
    a2[1] = (v4f){0.f, 0.f, 0.f, 0.f};
#pragma unroll
    for (int ks = 0; ks < 2; ks++) {
        v8s av = *(const v8s*)&Hs[wave * 16 + n16][ks * 32 + q * 8];
#pragma unroll
        for (int t = 0; t < 2; t++) {
            v8s bv = *(const v8s*)&W2t[(size_t)(t * 16 + n16) * 64 + ks * 32 + q * 8];
            a2[t] = __builtin_amdgcn_mfma_f32_16x16x32_bf16(av, bv, a2[t], 0, 0, 0);
        }
    }
    int rbase = node0 + wave * 16 + q * 4;
#pragma unroll
    for (int r = 0; r < 4; r++) {
        int row = rbase + r;
        if (row < N) {
#pragma unroll
            for (int t = 0; t < 2; t++)
                out[(size_t)row * 32 + t * 16 + n16] = a2[t][r] + b2[t * 16 + n16];
        }
    }
}

extern "C" void kernel_launch(void* const* d_in, const int* in_sizes, int n_in,
                              void* d_out, int out_size, void* d_ws, size_t ws_size,
                              hipStream_t stream) {
    const float* features = (const float*)d_in[0];
    const int* src = (const int*)d_in[1];
    const int* dst = (const int*)d_in[2];
    const float* W1 = (const float*)d_in[4];
    const float* b1 = (const float*)d_in[5];
    const float* W2 = (const float*)d_in[6];
    const float* b2 = (const float*)d_in[7];
    const float* Wm1 = (const float*)d_in[8];
    const float* bm1 = (const float*)d_in[9];
    const float* Wm2 = (const float*)d_in[10];
    const float* bm2 = (const float*)d_in[11];
    float* out = (float*)d_out;

    int N = in_sizes[0] / 64;
    int E = in_sizes[1];
    int NB = (N + BSZ - 1) >> BSH;

    float* ws = (float*)d_ws;
    float* dinv = ws;                           // [N]
    int* row_ptr = (int*)(dinv + N);            // [N+1]
    int* gbase = row_ptr + (N + 1);             // [1024]
    int* gcur = gbase + 1024;                   // [1024]
    int* col = gcur + 1024;                     // [E]
    int2* eb = (int2*)(((uintptr_t)(col + E) + 7) & ~(uintptr_t)7);  // [E]
    ushort_t* Fb  = (ushort_t*)(eb + E);        // [N*64] scaled
    ushort_t* X1b = Fb  + (size_t)N * 64;       // scaled
    ushort_t* X2b = X1b + (size_t)N * 64;       // unscaled
    ushort_t* H1b = X2b + (size_t)N * 64;       // scaled
    ushort_t* H2b = H1b + (size_t)N * 64;       // unscaled
    ushort_t* W1t = H2b + (size_t)N * 64;       // [64*192]
    ushort_t* W2t = W1t + 64 * 192;             // [64*192]
    ushort_t* Wm1t = W2t + 64 * 192;            // [64*64]
    ushort_t* Wm2t = Wm1t + 64 * 64;            // [32*64]

    int pblk = (N * 64 + 255) / 256;
    int gblk = (N + 63) / 64;
    int n4 = N * 16;
    int cblk = (n4 + 255) / 256;
    int bblk = (E + CHUNK - 1) / CHUNK;

    // weight prep (independent of graph)
    k_wprep<<<(30720 + 255) / 256, 256, 0, stream>>>(W1, W2, Wm1, Wm2, W1t, W2t, Wm1t, Wm2t);

    // CSR build
    hipMemsetAsync(gbase, 0, NB * sizeof(int), stream);
    k_bhist<<<512, 256, 0, stream>>>(dst, gbase, E, NB);
    k_bscan<<<1, 1024, 0, stream>>>(gbase, gcur, NB);
    k_bucket2<<<bblk, 256, 0, stream>>>(src, dst, gcur, eb, E, NB);
    k_local<<<NB, 256, 0, stream>>>(eb, gbase, col, row_ptr, dinv, N, E, NB);

    // scaled bf16 shadow of features
    k_tobf16<<<cblk, 256, 0, stream>>>((const float4*)features, dinv, (ushort4*)Fb, n4);

    // layer 1
    k_prop<1><<<pblk, 256, 0, stream>>>(Fb, row_ptr, col, dinv, nullptr, X1b, N);
    k_prop<2><<<pblk, 256, 0, stream>>>(X1b, row_ptr, col, dinv, Fb, X2b, N);
    k_cheb_mfma<true><<<gblk, 256, 0, stream>>>(Fb, X1b, X2b, dinv, W1t, b1, H1b, N);

    // layer 2
    k_prop<1><<<pblk, 256, 0, stream>>>(H1b, row_ptr, col, dinv, nullptr, X1b, N);
    k_prop<2><<<pblk, 256, 0, stream>>>(X1b, row_ptr, col, dinv, H1b, X2b, N);
    k_cheb_mfma<false><<<gblk, 256, 0, stream>>>(H1b, X1b, X2b, dinv, W2t, b2, H2b, N);

    // MLP head
    k_mlp_mfma<<<gblk, 256, 0, stream>>>(H2b, Wm1t, bm1, Wm2t, bm2, out, N);
}